// Round 5
// baseline (77274.084 us; speedup 1.0000x reference)
//
#include <hip/hip_runtime.h>
#include <math.h>

typedef float4 f4;

#define T_SEQ 2048
#define D_MOD 1024

__device__ __forceinline__ float gelu_f(float x){
    float u = 0.7978845608028654f*(x + 0.044715f*x*x*x);
    return 0.5f*x*(1.0f + tanhf(u));
}

// C[M,N] = act(A[M,K] @ W[K,N] + bias) (+ res)
// 64x128 block tile, 4x8 per thread, BK=32, reg-prefetched.
// Accumulation strictly k-sequential per output -> bitwise stable.
__global__ __launch_bounds__(256) void gemm128(
    const float* __restrict__ A, const float* __restrict__ W,
    const float* __restrict__ bias, const float* __restrict__ res,
    float* __restrict__ C, int M, int N, int K, int act, int hasres)
{
    __shared__ float As[32][68];
    __shared__ float Ws[32][136];
    const int tid = threadIdx.x;
    const int row0 = blockIdx.y*64, col0 = blockIdx.x*128;
    const int ty = tid>>4, tx = tid&15;
    const int am = tid>>2, ak = (tid&3)*8;
    const int wk = tid>>3, wn = (tid&7)*16;
    const float* Ap = A + (size_t)(row0+am)*K + ak;
    const float* Wp = W + (size_t)wk*N + col0 + wn;

    f4 a0,a1,w0,w1,w2,w3;
    a0 = *(const f4*)(Ap);
    a1 = *(const f4*)(Ap + 4);
    w0 = *(const f4*)(Wp);
    w1 = *(const f4*)(Wp + 4);
    w2 = *(const f4*)(Wp + 8);
    w3 = *(const f4*)(Wp + 12);
    As[ak+0][am]=a0.x; As[ak+1][am]=a0.y; As[ak+2][am]=a0.z; As[ak+3][am]=a0.w;
    As[ak+4][am]=a1.x; As[ak+5][am]=a1.y; As[ak+6][am]=a1.z; As[ak+7][am]=a1.w;
    *(f4*)&Ws[wk][wn]    = w0;
    *(f4*)&Ws[wk][wn+4]  = w1;
    *(f4*)&Ws[wk][wn+8]  = w2;
    *(f4*)&Ws[wk][wn+12] = w3;
    __syncthreads();

    float acc[4][8];
    #pragma unroll
    for (int i=0;i<4;i++){
        #pragma unroll
        for (int j=0;j<8;j++) acc[i][j]=0.f;
    }

    int k0 = 0;
    while (true){
        const int kn = k0 + 32;
        const bool more = kn < K;
        if (more){
            a0 = *(const f4*)(Ap + kn);
            a1 = *(const f4*)(Ap + kn + 4);
            w0 = *(const f4*)(Wp + (size_t)kn*N);
            w1 = *(const f4*)(Wp + (size_t)kn*N + 4);
            w2 = *(const f4*)(Wp + (size_t)kn*N + 8);
            w3 = *(const f4*)(Wp + (size_t)kn*N + 12);
        }
        #pragma unroll
        for (int kk=0;kk<32;kk++){
            f4 a  = *(const f4*)&As[kk][ty*4];
            f4 wA = *(const f4*)&Ws[kk][tx*8];
            f4 wB = *(const f4*)&Ws[kk][tx*8+4];
            float ar[4] = {a.x,a.y,a.z,a.w};
            #pragma unroll
            for (int i=0;i<4;i++){
                acc[i][0] += ar[i]*wA.x;
                acc[i][1] += ar[i]*wA.y;
                acc[i][2] += ar[i]*wA.z;
                acc[i][3] += ar[i]*wA.w;
                acc[i][4] += ar[i]*wB.x;
                acc[i][5] += ar[i]*wB.y;
                acc[i][6] += ar[i]*wB.z;
                acc[i][7] += ar[i]*wB.w;
            }
        }
        __syncthreads();
        if (!more) break;
        As[ak+0][am]=a0.x; As[ak+1][am]=a0.y; As[ak+2][am]=a0.z; As[ak+3][am]=a0.w;
        As[ak+4][am]=a1.x; As[ak+5][am]=a1.y; As[ak+6][am]=a1.z; As[ak+7][am]=a1.w;
        *(f4*)&Ws[wk][wn]    = w0;
        *(f4*)&Ws[wk][wn+4]  = w1;
        *(f4*)&Ws[wk][wn+8]  = w2;
        *(f4*)&Ws[wk][wn+12] = w3;
        __syncthreads();
        k0 = kn;
    }

    #pragma unroll
    for (int i=0;i<4;i++){
        const int r = row0 + ty*4 + i;
        #pragma unroll
        for (int half=0; half<2; ++half){
            const int cb = col0 + tx*8 + half*4;
            f4 bv = *(const f4*)(bias + cb);
            float t0 = acc[i][half*4+0] + bv.x;
            float t1 = acc[i][half*4+1] + bv.y;
            float t2 = acc[i][half*4+2] + bv.z;
            float t3 = acc[i][half*4+3] + bv.w;
            if (act==1){ t0=fmaxf(t0,0.f); t1=fmaxf(t1,0.f); t2=fmaxf(t2,0.f); t3=fmaxf(t3,0.f); }
            else if (act==2){ t0=gelu_f(t0); t1=gelu_f(t1); t2=gelu_f(t2); t3=gelu_f(t3); }
            if (hasres){
                f4 rv = *(const f4*)(res + (size_t)r*N + cb);
                t0+=rv.x; t1+=rv.y; t2+=rv.z; t3+=rv.w;
            }
            f4 o; o.x=t0; o.y=t1; o.z=t2; o.w=t3;
            *(f4*)(C + (size_t)r*N + cb) = o;
        }
    }
}

__global__ __launch_bounds__(256) void lnrow(
    const float* __restrict__ X, const float* __restrict__ g,
    const float* __restrict__ b, float* __restrict__ out, float eps)
{
    __shared__ float red[4];
    const int row = blockIdx.x, tid = threadIdx.x;
    const float* xp = X + (size_t)row*D_MOD;
    f4 xv = *(const f4*)(xp + tid*4);
    float s = xv.x+xv.y+xv.z+xv.w;
    #pragma unroll
    for (int m=1;m<64;m<<=1) s += __shfl_xor(s, m);
    const int wid = tid>>6, lane = tid&63;
    if (lane==0) red[wid]=s;
    __syncthreads();
    float mean = (red[0]+red[1]+red[2]+red[3]) * (1.0f/1024.0f);
    __syncthreads();
    float d0=xv.x-mean, d1=xv.y-mean, d2=xv.z-mean, d3=xv.w-mean;
    float q = d0*d0+d1*d1+d2*d2+d3*d3;
    #pragma unroll
    for (int m=1;m<64;m<<=1) q += __shfl_xor(q, m);
    if (lane==0) red[wid]=q;
    __syncthreads();
    float var = (red[0]+red[1]+red[2]+red[3]) * (1.0f/1024.0f);
    float inv = rsqrtf(var + eps);
    f4 gv = *(const f4*)(g + tid*4);
    f4 bv = *(const f4*)(b + tid*4);
    f4 o;
    o.x = d0*inv*gv.x + bv.x;
    o.y = d1*inv*gv.y + bv.y;
    o.z = d2*inv*gv.z + bv.z;
    o.w = d3*inv*gv.w + bv.w;
    *(f4*)(out + (size_t)row*D_MOD + tid*4) = o;
}

// flash attention, QBLK=128, s-split=2. 512 threads.
// bid: h=bid&7 (XCD-local K/V), sh=(bid>>3)&1 (s-half), qt=bid>>4 -> q0=qt*128.
// thread: ty=tid>>4 (4 q-rows), s8=(tid>>1)&7 (8 s-rows), dh=tid&1 (64-d half).
// oa[4][16] f4 is an s8-partial accumulator, reduced via shfl at the end.
// K and V LDS tiles both swizzled: chunk stored at slot c ^ (row>>3).
__global__ __launch_bounds__(512,1) void attn128(
    const float* __restrict__ Q, const float* __restrict__ Kb,
    const float* __restrict__ Vb,
    float* __restrict__ OA0, float* __restrict__ OA1,
    float* __restrict__ ML0, float* __restrict__ ML1)
{
    __shared__ float qs[128][132];
    __shared__ float ks[64][132];
    __shared__ float vs[64][132];
    const int tid = threadIdx.x;
    const int h  = blockIdx.x & 7;
    const int sh = (blockIdx.x >> 3) & 1;
    const int q0 = (blockIdx.x >> 4) * 128;
    const int ty = tid >> 4;
    const int s8 = (tid >> 1) & 7;
    const int dh = tid & 1;
    const int c4 = tid & 31, rb = tid >> 5;
    const int tkey = ty & 7;
    const int sbase = sh * 1024;
    const float qscale = 0.08838834764831845f; // 1/sqrt(128)

    f4 kr[4], vr[4];
    #pragma unroll
    for (int j=0;j<4;j++){
        const int r = rb + 16*j;
        kr[j] = *(const f4*)(Kb + (size_t)(sbase+r)*D_MOD + h*128 + c4*4);
        vr[j] = *(const f4*)(Vb + (size_t)(sbase+r)*D_MOD + h*128 + c4*4);
    }
    for (int i=tid; i<4096; i+=512){
        const int r = i>>5, cc = i&31;
        f4 v = *(const f4*)(Q + (size_t)(q0+r)*D_MOD + h*128 + cc*4);
        v.x*=qscale; v.y*=qscale; v.z*=qscale; v.w*=qscale;
        ((f4*)&qs[r][0])[cc ^ ((r>>2)&7)] = v;
    }
    #pragma unroll
    for (int j=0;j<4;j++){
        const int r = rb + 16*j;
        const int key = (r>>3)&7;
        ((f4*)&ks[r][0])[c4 ^ key] = kr[j];
        ((f4*)&vs[r][0])[c4 ^ key] = vr[j];
    }
    #pragma unroll
    for (int j=0;j<4;j++){
        const int r = rb + 16*j;
        kr[j] = *(const f4*)(Kb + (size_t)(sbase+64+r)*D_MOD + h*128 + c4*4);
        vr[j] = *(const f4*)(Vb + (size_t)(sbase+64+r)*D_MOD + h*128 + c4*4);
    }
    __syncthreads();

    float mstat[4], lstat[4];
    f4 oa[4][16];
    #pragma unroll
    for (int q=0;q<4;q++){
        mstat[q] = -__builtin_inff(); lstat[q] = 0.f;
        #pragma unroll
        for (int c=0;c<16;c++){ oa[q][c].x=0.f; oa[q][c].y=0.f; oa[q][c].z=0.f; oa[q][c].w=0.f; }
    }

    for (int t=0; t<16; ++t){
        // ---- QK^T (d-half partial) ----
        float acc[4][8];
        #pragma unroll
        for (int q=0;q<4;q++){
            #pragma unroll
            for (int k=0;k<8;k++) acc[q][k]=0.f;
        }
        #pragma unroll
        for (int i=0;i<16;i++){
            const int ch = dh*16 + i;
            f4 qv[4];
            #pragma unroll
            for (int q=0;q<4;q++) qv[q] = ((const f4*)&qs[ty*4+q][0])[ch ^ tkey];
            #pragma unroll
            for (int k=0;k<8;k++){
                f4 kv = ((const f4*)&ks[s8*8+k][0])[ch ^ s8];
                #pragma unroll
                for (int q=0;q<4;q++)
                    acc[q][k] += qv[q].x*kv.x + qv[q].y*kv.y + qv[q].z*kv.z + qv[q].w*kv.w;
            }
        }
        __syncthreads();   // b1: ks free

        if (t < 15){
            #pragma unroll
            for (int j=0;j<4;j++){
                const int r = rb + 16*j;
                ((f4*)&ks[r][0])[c4 ^ ((r>>3)&7)] = kr[j];
            }
            if (t+2 < 16){
                #pragma unroll
                for (int j=0;j<4;j++){
                    const int gr = sbase + (t+2)*64 + rb + 16*j;
                    kr[j] = *(const f4*)(Kb + (size_t)gr*D_MOD + h*128 + c4*4);
                }
            }
        }

        // ---- dh pair-reduce + online softmax ----
        #pragma unroll
        for (int q=0;q<4;q++){
            #pragma unroll
            for (int k=0;k<8;k++) acc[q][k] += __shfl_xor(acc[q][k], 1);
            float tm = acc[q][0];
            #pragma unroll
            for (int k=1;k<8;k++) tm = fmaxf(tm, acc[q][k]);
            tm = fmaxf(tm, __shfl_xor(tm,2));
            tm = fmaxf(tm, __shfl_xor(tm,4));
            tm = fmaxf(tm, __shfl_xor(tm,8));
            const float mn = fmaxf(mstat[q], tm);
            const float sc = __expf(mstat[q] - mn);
            float rs = 0.f;
            #pragma unroll
            for (int k=0;k<8;k++){
                const float p = __expf(acc[q][k] - mn);
                acc[q][k] = p; rs += p;
            }
            rs += __shfl_xor(rs,2); rs += __shfl_xor(rs,4); rs += __shfl_xor(rs,8);
            lstat[q] = lstat[q]*sc + rs;
            mstat[q] = mn;
            #pragma unroll
            for (int c=0;c<16;c++){
                oa[q][c].x*=sc; oa[q][c].y*=sc; oa[q][c].z*=sc; oa[q][c].w*=sc;
            }
        }

        // ---- PV (s8-partial, static oa index) ----
        #pragma unroll
        for (int k=0;k<8;k++){
            const f4* vrow = (const f4*)&vs[s8*8+k][0];
            const float p0=acc[0][k], p1=acc[1][k], p2=acc[2][k], p3=acc[3][k];
            #pragma unroll
            for (int c=0;c<16;c++){
                const f4 v = vrow[(dh*16 + c) ^ s8];
                oa[0][c].x+=p0*v.x; oa[0][c].y+=p0*v.y; oa[0][c].z+=p0*v.z; oa[0][c].w+=p0*v.w;
                oa[1][c].x+=p1*v.x; oa[1][c].y+=p1*v.y; oa[1][c].z+=p1*v.z; oa[1][c].w+=p1*v.w;
                oa[2][c].x+=p2*v.x; oa[2][c].y+=p2*v.y; oa[2][c].z+=p2*v.z; oa[2][c].w+=p2*v.w;
                oa[3][c].x+=p3*v.x; oa[3][c].y+=p3*v.y; oa[3][c].z+=p3*v.z; oa[3][c].w+=p3*v.w;
            }
        }
        __syncthreads();   // b2: vs free

        if (t < 15){
            #pragma unroll
            for (int j=0;j<4;j++){
                const int r = rb + 16*j;
                ((f4*)&vs[r][0])[c4 ^ ((r>>3)&7)] = vr[j];
            }
            if (t+2 < 16){
                #pragma unroll
                for (int j=0;j<4;j++){
                    const int gr = sbase + (t+2)*64 + rb + 16*j;
                    vr[j] = *(const f4*)(Vb + (size_t)gr*D_MOD + h*128 + c4*4);
                }
            }
        }
    }

    // ---- reduce oa over the 8 s8 lanes (masks 2,4,8) ----
    #pragma unroll
    for (int q=0;q<4;q++){
        #pragma unroll
        for (int c=0;c<16;c++){
            oa[q][c].x += __shfl_xor(oa[q][c].x, 2);
            oa[q][c].y += __shfl_xor(oa[q][c].y, 2);
            oa[q][c].z += __shfl_xor(oa[q][c].z, 2);
            oa[q][c].w += __shfl_xor(oa[q][c].w, 2);
            oa[q][c].x += __shfl_xor(oa[q][c].x, 4);
            oa[q][c].y += __shfl_xor(oa[q][c].y, 4);
            oa[q][c].z += __shfl_xor(oa[q][c].z, 4);
            oa[q][c].w += __shfl_xor(oa[q][c].w, 4);
            oa[q][c].x += __shfl_xor(oa[q][c].x, 8);
            oa[q][c].y += __shfl_xor(oa[q][c].y, 8);
            oa[q][c].z += __shfl_xor(oa[q][c].z, 8);
            oa[q][c].w += __shfl_xor(oa[q][c].w, 8);
        }
    }

    float* OAp = sh ? OA1 : OA0;
    float* MLp = sh ? ML1 : ML0;
    if (s8 == 0){
        #pragma unroll
        for (int q=0;q<4;q++){
            float* dst = OAp + (size_t)(q0+ty*4+q)*D_MOD + h*128 + dh*64;
            #pragma unroll
            for (int c=0;c<16;c++) *(f4*)(dst + c*4) = oa[q][c];
        }
        if (dh == 0){
            #pragma unroll
            for (int q=0;q<4;q++){
                MLp[(size_t)(q0+ty*4+q)*16 + h*2 + 0] = mstat[q];
                MLp[(size_t)(q0+ty*4+q)*16 + h*2 + 1] = lstat[q];
            }
        }
    }
}

// flash-combine of the two s-halves + the bias-KV token (exact softmax algebra)
__global__ __launch_bounds__(256) void attn_combine(
    const float* __restrict__ Q, const float* __restrict__ kbias,
    const float* __restrict__ vbias,
    const float* __restrict__ OA0, const float* __restrict__ OA1,
    const float* __restrict__ ML0, const float* __restrict__ ML1,
    float* __restrict__ O)
{
    const int row = blockIdx.x, t = threadIdx.x;
    const int h = t >> 5;
    const int cc = t & 31;
    const float qscale = 0.08838834764831845f;
    const f4 qv = *(const f4*)(Q + (size_t)row*D_MOD + h*128 + cc*4);
    const f4 kb = *(const f4*)(kbias + h*128 + cc*4);
    float part = qv.x*kb.x + qv.y*kb.y + qv.z*kb.z + qv.w*kb.w;
    part += __shfl_xor(part,1); part += __shfl_xor(part,2);
    part += __shfl_xor(part,4); part += __shfl_xor(part,8);
    part += __shfl_xor(part,16);
    const float sb = part * qscale;
    const float m0 = ML0[(size_t)row*16 + h*2], l0 = ML0[(size_t)row*16 + h*2 + 1];
    const float m1 = ML1[(size_t)row*16 + h*2], l1 = ML1[(size_t)row*16 + h*2 + 1];
    const float M  = fmaxf(fmaxf(m0, m1), sb);
    const float w0 = __expf(m0 - M), w1 = __expf(m1 - M), wb = __expf(sb - M);
    const float inv = 1.0f / (w0*l0 + w1*l1 + wb);
    const f4 o0 = *(const f4*)(OA0 + (size_t)row*D_MOD + t*4);
    const f4 o1 = *(const f4*)(OA1 + (size_t)row*D_MOD + t*4);
    const f4 vb = *(const f4*)(vbias + h*128 + cc*4);
    f4 o;
    o.x = (o0.x*w0 + o1.x*w1 + vb.x*wb) * inv;
    o.y = (o0.y*w0 + o1.y*w1 + vb.y*wb) * inv;
    o.z = (o0.z*w0 + o1.z*w1 + vb.z*wb) * inv;
    o.w = (o0.w*w0 + o1.w*w1 + vb.w*wb) * inv;
    *(f4*)(O + (size_t)row*D_MOD + t*4) = o;
}

__global__ __launch_bounds__(64) void locate_head(
    const float* __restrict__ mid, const float* __restrict__ W2,
    const float* __restrict__ b2, float* __restrict__ loc_ws,
    float* __restrict__ loc_out)
{
    const int row = blockIdx.x, lane = threadIdx.x;
    const float* m = mid + (size_t)row*512;
    f4 v0 = *(const f4*)(m + lane*8);
    f4 v1 = *(const f4*)(m + lane*8 + 4);
    f4 w0 = *(const f4*)(W2 + lane*8);
    f4 w1 = *(const f4*)(W2 + lane*8 + 4);
    float s = v0.x*w0.x + v0.y*w0.y + v0.z*w0.z + v0.w*w0.w
            + v1.x*w1.x + v1.y*w1.y + v1.z*w1.z + v1.w*w1.w;
    #pragma unroll
    for (int mm=1; mm<64; mm<<=1) s += __shfl_xor(s, mm);
    if (lane==0){
        float z = s + b2[0];
        float l = 1.0f/(1.0f + expf(-z));
        loc_ws[row] = l;
        loc_out[row] = l;
    }
}

__global__ __launch_bounds__(1024) void segscan(
    const float* __restrict__ located, const float* __restrict__ thrp,
    float* __restrict__ out_segid, float* __restrict__ out_segtype,
    float* __restrict__ out_numseg, int* __restrict__ wsi)
{
    __shared__ int clips[2048];
    __shared__ int segid[2048];
    __shared__ int sstart[2049];
    __shared__ int wsum[16];
    const int tid = threadIdx.x;
    const float thr = *thrp;
    for (int t=tid; t<2048; t+=1024) clips[t] = (located[t] > thr) ? 1 : 0;
    __syncthreads();
    const int t0 = tid*2, t1 = t0+1;
    int f0 = (t0==0) ? 0 : (clips[t0]!=clips[t0-1] ? 1 : 0);
    int f1 = (clips[t1]!=clips[t1-1] ? 1 : 0);
    int e0 = f0, e1 = f0+f1;
    const int lane = tid&63, wid = tid>>6;
    int v = e1;
    #pragma unroll
    for (int off=1; off<64; off<<=1){
        int u = __shfl_up(v, off, 64);
        if (lane>=off) v += u;
    }
    if (lane==63) wsum[wid] = v;
    __syncthreads();
    if (tid < 16){
        int w = wsum[tid];
        #pragma unroll
        for (int off=1; off<16; off<<=1){
            int u = __shfl_up(w, off, 16);
            if (tid>=off) w += u;
        }
        wsum[tid] = w;
    }
    __syncthreads();
    int base = (wid>0 ? wsum[wid-1] : 0) + (v - e1);
    segid[t0] = base + e0;
    segid[t1] = base + e1;
    __syncthreads();
    const int ns = segid[2047] + 1;
    for (int t=tid; t<2048; t+=1024){
        if (t==0 || segid[t]!=segid[t-1]) sstart[segid[t]] = t;
    }
    if (tid==0) sstart[ns] = 2048;
    __syncthreads();
    for (int t=tid; t<2048; t+=1024) out_segid[t] = (float)segid[t];
    for (int s=tid; s<2048; s+=1024)
        out_segtype[s] = (s<ns) ? (float)clips[sstart[s]] : -2147483648.0f;
    if (tid==0){ out_numseg[0] = (float)ns; wsi[0] = ns; }
    for (int s=tid; s<=2048; s+=1024) wsi[2+s] = (s<=ns) ? sstart[s] : 0;
}

__global__ __launch_bounds__(256) void segpool(
    const float* __restrict__ V, const float* __restrict__ A,
    const int* __restrict__ wsi, float* __restrict__ out_vid,
    float* __restrict__ out_aud)
{
    const int s = blockIdx.x;
    const int c = threadIdx.x*4;
    const int ns = wsi[0];
    f4 vv; vv.x=0.f; vv.y=0.f; vv.z=0.f; vv.w=0.f;
    f4 av = vv;
    if (s < ns){
        const int st = wsi[2+s], en = wsi[2+s+1];
        for (int r=st; r<en; ++r){
            f4 x = *(const f4*)(V + (size_t)r*D_MOD + c);
            vv.x+=x.x; vv.y+=x.y; vv.z+=x.z; vv.w+=x.w;
            f4 y = *(const f4*)(A + (size_t)r*D_MOD + c);
            av.x+=y.x; av.y+=y.y; av.z+=y.z; av.w+=y.w;
        }
        const float inv = 1.0f/(float)(en-st);
        vv.x*=inv; vv.y*=inv; vv.z*=inv; vv.w*=inv;
        av.x*=inv; av.y*=inv; av.z*=inv; av.w*=inv;
    }
    *(f4*)(out_vid + (size_t)s*D_MOD + c) = vv;
    *(f4*)(out_aud + (size_t)s*D_MOD + c) = av;
}

extern "C" void kernel_launch(void* const* d_in, const int* in_sizes, int n_in,
                              void* d_out, int out_size, void* d_ws, size_t ws_size,
                              hipStream_t stream) {
    (void)in_sizes; (void)n_in; (void)out_size; (void)ws_size;
    const float* video = (const float*)d_in[0];
    const float* audio = (const float*)d_in[1];
    const float* apW1  = (const float*)d_in[2];
    const float* apb1  = (const float*)d_in[3];
    const float* apW2  = (const float*)d_in[4];
    const float* apb2  = (const float*)d_in[5];
    const float* vpW1  = (const float*)d_in[6];
    const float* vpb1  = (const float*)d_in[7];
    const float* vpW2  = (const float*)d_in[8];
    const float* vpb2  = (const float*)d_in[9];
    const float* preg  = (const float*)d_in[10];
    const float* preb  = (const float*)d_in[11];
    const float* bWq   = (const float*)d_in[12];
    const float* bbq   = (const float*)d_in[13];
    const float* bWk   = (const float*)d_in[14];
    const float* bbk   = (const float*)d_in[15];
    const float* bWv   = (const float*)d_in[16];
    const float* bbv   = (const float*)d_in[17];
    const float* bWo   = (const float*)d_in[18];
    const float* bbo   = (const float*)d_in[19];
    const float* bbiask= (const float*)d_in[20];
    const float* bbiasv= (const float*)d_in[21];
    const float* bg1   = (const float*)d_in[22];
    const float* bb1   = (const float*)d_in[23];
    const float* bg2   = (const float*)d_in[24];
    const float* bb2   = (const float*)d_in[25];
    const float* bmW1  = (const float*)d_in[26];
    const float* bmb1  = (const float*)d_in[27];
    const float* bmW2  = (const float*)d_in[28];
    const float* bmb2  = (const float*)d_in[29];
    const float* lhW1  = (const float*)d_in[30];
    const float* lhb1  = (const float*)d_in[31];
    const float* lhW2  = (const float*)d_in[32];
    const float* lhb2  = (const float*)d_in[33];
    const float* thrp  = (const float*)d_in[34];

    float* ws = (float*)d_ws;
    float* V    = ws + 0;
    float* Abuf = ws + 2097152;
    float* X    = ws + 4194304;
    float* H    = ws + 6291456;             // also OA1 during attention (dead there)
    float* Q    = ws + 8388608;
    float* Kb   = ws + 10485760;            // 2048*1024
    float* Vb   = ws + 12582912;            // 2048*1024
    float* Obuf = ws + 14680064;            // 2048*1024; also OA0 during attention
    float* M4   = ws + 8388608;             // 2048*4096, aliases Q..Obuf
    float* M512 = ws + 16777216;            // 2048*512
    float* LOC  = ws + 17825792;            // 2048
    int*   WSI  = (int*)(ws + 17827840);    // 2051 ints
    float* ML0  = ws + 17829952;            // 2048*8*2
    float* ML1  = ws + 17862720;            // 2048*8*2

    float* out = (float*)d_out;
    float* out_vid     = out + 0;
    float* out_aud     = out + 2097152;
    float* out_loc     = out + 4194304;
    float* out_segid   = out + 4196352;
    float* out_segtype = out + 4198400;
    float* out_numseg  = out + 4200448;

    const dim3 B256(256);
    #define GRID128(M,N) dim3((N)/128,(M)/64)

    // projectors
    gemm128<<<GRID128(2048,512), B256, 0, stream>>>(audio, apW1, apb1, nullptr, M512, 2048,512,128, 1,0);
    gemm128<<<GRID128(2048,1024),B256, 0, stream>>>(M512, apW2, apb2, nullptr, Abuf, 2048,1024,512, 0,0);
    gemm128<<<GRID128(2048,512), B256, 0, stream>>>(video, vpW1, vpb1, nullptr, M512, 2048,512,1024, 1,0);
    gemm128<<<GRID128(2048,1024),B256, 0, stream>>>(M512, vpW2, vpb2, nullptr, V,    2048,1024,512, 0,0);
    lnrow<<<2048, B256, 0, stream>>>(Abuf, preg, preb, X, 1e-6f);

    for (int l=0; l<8; ++l){
        const size_t wo = (size_t)l*1024*1024;
        const size_t bo = (size_t)l*1024;
        const size_t mo1 = (size_t)l*1024*4096;
        lnrow<<<2048, B256, 0, stream>>>(X, bg1+bo, bb1+bo, H, 1e-5f);
        gemm128<<<GRID128(2048,1024),B256,0,stream>>>(H, bWq+wo, bbq+bo, nullptr, Q,  2048,1024,1024, 0,0);
        gemm128<<<GRID128(2048,1024),B256,0,stream>>>(V, bWk+wo, bbk+bo, nullptr, Kb, 2048,1024,1024, 0,0);
        gemm128<<<GRID128(2048,1024),B256,0,stream>>>(V, bWv+wo, bbv+bo, nullptr, Vb, 2048,1024,1024, 0,0);
        attn128<<<256, dim3(512), 0, stream>>>(Q, Kb, Vb, Obuf, H, ML0, ML1);
        attn_combine<<<2048, B256, 0, stream>>>(Q, bbiask+bo, bbiasv+bo, Obuf, H, ML0, ML1, Obuf);
        gemm128<<<GRID128(2048,1024),B256,0,stream>>>(Obuf, bWo+wo, bbo+bo, X, X, 2048,1024,1024, 0,1);
        lnrow<<<2048, B256, 0, stream>>>(X, bg2+bo, bb2+bo, H, 1e-5f);
        gemm128<<<GRID128(2048,4096),B256,0,stream>>>(H, bmW1+mo1, bmb1+(size_t)l*4096, nullptr, M4, 2048,4096,1024, 2,0);
        gemm128<<<GRID128(2048,1024),B256,0,stream>>>(M4, bmW2+mo1, bmb2+bo, X, X, 2048,1024,4096, 0,1);
    }

    gemm128<<<GRID128(2048,512), B256, 0, stream>>>(X, lhW1, lhb1, nullptr, M512, 2048,512,1024, 1,0);
    locate_head<<<2048, dim3(64), 0, stream>>>(M512, lhW2, lhb2, LOC, out_loc);
    segscan<<<1, dim3(1024), 0, stream>>>(LOC, thrp, out_segid, out_segtype, out_numseg, WSI);
    segpool<<<2048, B256, 0, stream>>>(V, Abuf, WSI, out_vid, out_aud);
}

// Round 6
// 9329.285 us; speedup vs baseline: 8.2830x; 8.2830x over previous
//
#include <hip/hip_runtime.h>
#include <math.h>

typedef float4 f4;

#define T_SEQ 2048
#define D_MOD 1024

__device__ __forceinline__ float gelu_f(float x){
    float u = 0.7978845608028654f*(x + 0.044715f*x*x*x);
    return 0.5f*x*(1.0f + tanhf(u));
}

// C[M,N] = act(A[M,K] @ W[K,N] + bias) (+ res)
__global__ __launch_bounds__(256) void gemm128(
    const float* __restrict__ A, const float* __restrict__ W,
    const float* __restrict__ bias, const float* __restrict__ res,
    float* __restrict__ C, int M, int N, int K, int act, int hasres)
{
    __shared__ float As[32][68];
    __shared__ float Ws[32][136];
    const int tid = threadIdx.x;
    const int row0 = blockIdx.y*64, col0 = blockIdx.x*128;
    const int ty = tid>>4, tx = tid&15;
    const int am = tid>>2, ak = (tid&3)*8;
    const int wk = tid>>3, wn = (tid&7)*16;
    const float* Ap = A + (size_t)(row0+am)*K + ak;
    const float* Wp = W + (size_t)wk*N + col0 + wn;

    f4 a0,a1,w0,w1,w2,w3;
    a0 = *(const f4*)(Ap);
    a1 = *(const f4*)(Ap + 4);
    w0 = *(const f4*)(Wp);
    w1 = *(const f4*)(Wp + 4);
    w2 = *(const f4*)(Wp + 8);
    w3 = *(const f4*)(Wp + 12);
    As[ak+0][am]=a0.x; As[ak+1][am]=a0.y; As[ak+2][am]=a0.z; As[ak+3][am]=a0.w;
    As[ak+4][am]=a1.x; As[ak+5][am]=a1.y; As[ak+6][am]=a1.z; As[ak+7][am]=a1.w;
    *(f4*)&Ws[wk][wn]    = w0;
    *(f4*)&Ws[wk][wn+4]  = w1;
    *(f4*)&Ws[wk][wn+8]  = w2;
    *(f4*)&Ws[wk][wn+12] = w3;
    __syncthreads();

    float acc[4][8];
    #pragma unroll
    for (int i=0;i<4;i++){
        #pragma unroll
        for (int j=0;j<8;j++) acc[i][j]=0.f;
    }

    int k0 = 0;
    while (true){
        const int kn = k0 + 32;
        const bool more = kn < K;
        if (more){
            a0 = *(const f4*)(Ap + kn);
            a1 = *(const f4*)(Ap + kn + 4);
            w0 = *(const f4*)(Wp + (size_t)kn*N);
            w1 = *(const f4*)(Wp + (size_t)kn*N + 4);
            w2 = *(const f4*)(Wp + (size_t)kn*N + 8);
            w3 = *(const f4*)(Wp + (size_t)kn*N + 12);
        }
        #pragma unroll
        for (int kk=0;kk<32;kk++){
            f4 a  = *(const f4*)&As[kk][ty*4];
            f4 wA = *(const f4*)&Ws[kk][tx*8];
            f4 wB = *(const f4*)&Ws[kk][tx*8+4];
            float ar[4] = {a.x,a.y,a.z,a.w};
            #pragma unroll
            for (int i=0;i<4;i++){
                acc[i][0] += ar[i]*wA.x;
                acc[i][1] += ar[i]*wA.y;
                acc[i][2] += ar[i]*wA.z;
                acc[i][3] += ar[i]*wA.w;
                acc[i][4] += ar[i]*wB.x;
                acc[i][5] += ar[i]*wB.y;
                acc[i][6] += ar[i]*wB.z;
                acc[i][7] += ar[i]*wB.w;
            }
        }
        __syncthreads();
        if (!more) break;
        As[ak+0][am]=a0.x; As[ak+1][am]=a0.y; As[ak+2][am]=a0.z; As[ak+3][am]=a0.w;
        As[ak+4][am]=a1.x; As[ak+5][am]=a1.y; As[ak+6][am]=a1.z; As[ak+7][am]=a1.w;
        *(f4*)&Ws[wk][wn]    = w0;
        *(f4*)&Ws[wk][wn+4]  = w1;
        *(f4*)&Ws[wk][wn+8]  = w2;
        *(f4*)&Ws[wk][wn+12] = w3;
        __syncthreads();
        k0 = kn;
    }

    #pragma unroll
    for (int i=0;i<4;i++){
        const int r = row0 + ty*4 + i;
        #pragma unroll
        for (int half=0; half<2; ++half){
            const int cb = col0 + tx*8 + half*4;
            f4 bv = *(const f4*)(bias + cb);
            float t0 = acc[i][half*4+0] + bv.x;
            float t1 = acc[i][half*4+1] + bv.y;
            float t2 = acc[i][half*4+2] + bv.z;
            float t3 = acc[i][half*4+3] + bv.w;
            if (act==1){ t0=fmaxf(t0,0.f); t1=fmaxf(t1,0.f); t2=fmaxf(t2,0.f); t3=fmaxf(t3,0.f); }
            else if (act==2){ t0=gelu_f(t0); t1=gelu_f(t1); t2=gelu_f(t2); t3=gelu_f(t3); }
            if (hasres){
                f4 rv = *(const f4*)(res + (size_t)r*N + cb);
                t0+=rv.x; t1+=rv.y; t2+=rv.z; t3+=rv.w;
            }
            f4 o; o.x=t0; o.y=t1; o.z=t2; o.w=t3;
            *(f4*)(C + (size_t)r*N + cb) = o;
        }
    }
}

__global__ __launch_bounds__(256) void lnrow(
    const float* __restrict__ X, const float* __restrict__ g,
    const float* __restrict__ b, float* __restrict__ out, float eps)
{
    __shared__ float red[4];
    const int row = blockIdx.x, tid = threadIdx.x;
    const float* xp = X + (size_t)row*D_MOD;
    f4 xv = *(const f4*)(xp + tid*4);
    float s = xv.x+xv.y+xv.z+xv.w;
    #pragma unroll
    for (int m=1;m<64;m<<=1) s += __shfl_xor(s, m);
    const int wid = tid>>6, lane = tid&63;
    if (lane==0) red[wid]=s;
    __syncthreads();
    float mean = (red[0]+red[1]+red[2]+red[3]) * (1.0f/1024.0f);
    __syncthreads();
    float d0=xv.x-mean, d1=xv.y-mean, d2=xv.z-mean, d3=xv.w-mean;
    float q = d0*d0+d1*d1+d2*d2+d3*d3;
    #pragma unroll
    for (int m=1;m<64;m<<=1) q += __shfl_xor(q, m);
    if (lane==0) red[wid]=q;
    __syncthreads();
    float var = (red[0]+red[1]+red[2]+red[3]) * (1.0f/1024.0f);
    float inv = rsqrtf(var + eps);
    f4 gv = *(const f4*)(g + tid*4);
    f4 bv = *(const f4*)(b + tid*4);
    f4 o;
    o.x = d0*inv*gv.x + bv.x;
    o.y = d1*inv*gv.y + bv.y;
    o.z = d2*inv*gv.z + bv.z;
    o.w = d3*inv*gv.w + bv.w;
    *(f4*)(out + (size_t)row*D_MOD + tid*4) = o;
}

// flash attention, QBLK=128, s-split=2, 512 threads (8 waves, 2/SIMD).
// bid: h=bid&7, sh=(bid>>3)&1, q0=(bid>>4)*128.
// QK decomposition: qg=tid>>5 (8 q-rows), sg=(tid>>1)&15 (4 s-rows), dh=tid&1 (64-d half).
// PV decomposition: qg2=tid>>4 (4 q-rows), dg=tid&15 (chunks 2dg,2dg+1).
// P is stored TRANSPOSED [s][q] into the ks region (dead between b1 and b3).
// Register budget: acc 32 + oa 32 + kr/vr 32 + stats 24 ~ 170 VGPR (no spill at 2 waves/SIMD).
#define KS4(r) ((f4*)&ks[r][0])
#define VS4(r) ((f4*)&vs[r][0])
#define QS4(r) ((f4*)&qs[r][0])
__global__ __launch_bounds__(512,2) void attn128s(
    const float* __restrict__ Q, const float* __restrict__ Kb,
    const float* __restrict__ Vb,
    float* __restrict__ OA0, float* __restrict__ OA1,
    float* __restrict__ ML0, float* __restrict__ ML1)
{
    __shared__ float qs[128][132];
    __shared__ float ks[64][132];   // K tile; P[s][q] alias between b1..b3
    __shared__ float vs[64][132];
    __shared__ float scs[128];
    const int tid = threadIdx.x;
    const int h  = blockIdx.x & 7;
    const int sh = (blockIdx.x >> 3) & 1;
    const int q0 = (blockIdx.x >> 4) * 128;
    const int dh = tid & 1;
    const int sg = (tid >> 1) & 15;
    const int qg = tid >> 5;
    const int qg2 = tid >> 4;
    const int dg  = tid & 15;
    const int c4 = tid & 31, rb = tid >> 5;
    const int sbase = sh * 1024;
    const float qscale = 0.08838834764831845f; // 1/sqrt(128)

    f4 kr[4], vr[4];
    #pragma unroll
    for (int j=0;j<4;j++){
        const int r = rb + 16*j;
        kr[j] = *(const f4*)(Kb + (size_t)(sbase+r)*D_MOD + h*128 + c4*4);
        vr[j] = *(const f4*)(Vb + (size_t)(sbase+r)*D_MOD + h*128 + c4*4);
    }
    #pragma unroll
    for (int kq=0;kq<8;kq++){
        const int i = tid + kq*512;
        const int r = i>>5, cc = i&31;
        f4 v = *(const f4*)(Q + (size_t)(q0+r)*D_MOD + h*128 + cc*4);
        v.x*=qscale; v.y*=qscale; v.z*=qscale; v.w*=qscale;
        QS4(r)[cc ^ ((r>>2)&7)] = v;
    }
    #pragma unroll
    for (int j=0;j<4;j++){
        const int r = rb + 16*j;
        const int key = (r>>2)&7;
        KS4(r)[c4 ^ key] = kr[j];
        VS4(r)[c4 ^ key] = vr[j];
    }
    #pragma unroll
    for (int j=0;j<4;j++){
        const int r = rb + 16*j;
        kr[j] = *(const f4*)(Kb + (size_t)(sbase+64+r)*D_MOD + h*128 + c4*4);
        vr[j] = *(const f4*)(Vb + (size_t)(sbase+64+r)*D_MOD + h*128 + c4*4);
    }
    __syncthreads();

    float mstat[8], lstat[8];
    f4 oa[4][2];
    #pragma unroll
    for (int i=0;i<8;i++){ mstat[i] = -__builtin_inff(); lstat[i] = 0.f; }
    #pragma unroll
    for (int i=0;i<4;i++){
        #pragma unroll
        for (int b=0;b<2;b++){ oa[i][b].x=0.f; oa[i][b].y=0.f; oa[i][b].z=0.f; oa[i][b].w=0.f; }
    }

    for (int t=0; t<16; ++t){
        // ---- QK^T: acc[8q][4s] over this thread's 64-d half ----
        float acc[8][4];
        #pragma unroll
        for (int i=0;i<8;i++){
            #pragma unroll
            for (int j=0;j<4;j++) acc[i][j]=0.f;
        }
        #pragma unroll
        for (int c=0;c<16;c++){
            const int ch = dh*16 + c;
            f4 kv[4];
            #pragma unroll
            for (int j=0;j<4;j++) kv[j] = KS4(sg*4+j)[ch ^ (sg&7)];
            #pragma unroll
            for (int i=0;i<8;i++){
                const f4 qv = QS4(qg*8+i)[ch ^ ((qg*2+(i>>2))&7)];
                #pragma unroll
                for (int j=0;j<4;j++)
                    acc[i][j] += qv.x*kv[j].x + qv.y*kv[j].y + qv.z*kv[j].z + qv.w*kv[j].w;
            }
        }
        __syncthreads();   // b1: ks region free (K_t consumed)

        // ---- combine d-halves + online softmax ----
        float scarr[8];
        #pragma unroll
        for (int i=0;i<8;i++){
            #pragma unroll
            for (int j=0;j<4;j++) acc[i][j] += __shfl_xor(acc[i][j], 1);
            float tm = fmaxf(fmaxf(acc[i][0],acc[i][1]), fmaxf(acc[i][2],acc[i][3]));
            tm = fmaxf(tm, __shfl_xor(tm,2));
            tm = fmaxf(tm, __shfl_xor(tm,4));
            tm = fmaxf(tm, __shfl_xor(tm,8));
            tm = fmaxf(tm, __shfl_xor(tm,16));
            const float mn = fmaxf(mstat[i], tm);
            const float sc = __expf(mstat[i] - mn);
            float rs = 0.f;
            #pragma unroll
            for (int j=0;j<4;j++){
                const float p = __expf(acc[i][j] - mn);
                acc[i][j] = p; rs += p;
            }
            rs += __shfl_xor(rs,2); rs += __shfl_xor(rs,4);
            rs += __shfl_xor(rs,8); rs += __shfl_xor(rs,16);
            lstat[i] = lstat[i]*sc + rs;
            mstat[i] = mn;
            scarr[i] = sc;
        }
        // write P (transposed [s][q]) into ks region; write per-q scales
        if (dh == 0){
            #pragma unroll
            for (int j=0;j<4;j++){
                const int s = sg*4 + j;
                f4 pw0, pw1;
                pw0.x=acc[0][j]; pw0.y=acc[1][j]; pw0.z=acc[2][j]; pw0.w=acc[3][j];
                pw1.x=acc[4][j]; pw1.y=acc[5][j]; pw1.z=acc[6][j]; pw1.w=acc[7][j];
                KS4(s)[2*qg]   = pw0;
                KS4(s)[2*qg+1] = pw1;
            }
            if (sg == 0){
                f4 s0, s1;
                s0.x=scarr[0]; s0.y=scarr[1]; s0.z=scarr[2]; s0.w=scarr[3];
                s1.x=scarr[4]; s1.y=scarr[5]; s1.z=scarr[6]; s1.w=scarr[7];
                ((f4*)scs)[2*qg]   = s0;
                ((f4*)scs)[2*qg+1] = s1;
            }
        }
        __syncthreads();   // b2: P + scales ready

        // ---- PV: thread owns 4 q rows x 8 d; iterate all 64 s ----
        {
            const f4 scf = ((const f4*)scs)[qg2];
            #pragma unroll
            for (int b=0;b<2;b++){
                oa[0][b].x*=scf.x; oa[0][b].y*=scf.x; oa[0][b].z*=scf.x; oa[0][b].w*=scf.x;
                oa[1][b].x*=scf.y; oa[1][b].y*=scf.y; oa[1][b].z*=scf.y; oa[1][b].w*=scf.y;
                oa[2][b].x*=scf.z; oa[2][b].y*=scf.z; oa[2][b].z*=scf.z; oa[2][b].w*=scf.z;
                oa[3][b].x*=scf.w; oa[3][b].y*=scf.w; oa[3][b].z*=scf.w; oa[3][b].w*=scf.w;
            }
        }
        #pragma unroll 4
        for (int s=0; s<64; ++s){
            const int vkey = (s>>2)&7;
            const f4 pv = KS4(s)[qg2];
            const f4 v0 = VS4(s)[(2*dg)   ^ vkey];
            const f4 v1 = VS4(s)[(2*dg+1) ^ vkey];
            oa[0][0].x+=pv.x*v0.x; oa[0][0].y+=pv.x*v0.y; oa[0][0].z+=pv.x*v0.z; oa[0][0].w+=pv.x*v0.w;
            oa[0][1].x+=pv.x*v1.x; oa[0][1].y+=pv.x*v1.y; oa[0][1].z+=pv.x*v1.z; oa[0][1].w+=pv.x*v1.w;
            oa[1][0].x+=pv.y*v0.x; oa[1][0].y+=pv.y*v0.y; oa[1][0].z+=pv.y*v0.z; oa[1][0].w+=pv.y*v0.w;
            oa[1][1].x+=pv.y*v1.x; oa[1][1].y+=pv.y*v1.y; oa[1][1].z+=pv.y*v1.z; oa[1][1].w+=pv.y*v1.w;
            oa[2][0].x+=pv.z*v0.x; oa[2][0].y+=pv.z*v0.y; oa[2][0].z+=pv.z*v0.z; oa[2][0].w+=pv.z*v0.w;
            oa[2][1].x+=pv.z*v1.x; oa[2][1].y+=pv.z*v1.y; oa[2][1].z+=pv.z*v1.z; oa[2][1].w+=pv.z*v1.w;
            oa[3][0].x+=pv.w*v0.x; oa[3][0].y+=pv.w*v0.y; oa[3][0].z+=pv.w*v0.z; oa[3][0].w+=pv.w*v0.w;
            oa[3][1].x+=pv.w*v1.x; oa[3][1].y+=pv.w*v1.y; oa[3][1].z+=pv.w*v1.z; oa[3][1].w+=pv.w*v1.w;
        }
        __syncthreads();   // b3: ks (P) and vs (V_t) free

        if (t < 15){
            #pragma unroll
            for (int j=0;j<4;j++){
                const int r = rb + 16*j;
                const int key = (r>>2)&7;
                KS4(r)[c4 ^ key] = kr[j];
                VS4(r)[c4 ^ key] = vr[j];
            }
            if (t < 14){
                #pragma unroll
                for (int j=0;j<4;j++){
                    const int gr = sbase + (t+2)*64 + rb + 16*j;
                    kr[j] = *(const f4*)(Kb + (size_t)gr*D_MOD + h*128 + c4*4);
                    vr[j] = *(const f4*)(Vb + (size_t)gr*D_MOD + h*128 + c4*4);
                }
            }
        }
        __syncthreads();   // b4: K_{t+1}/V_{t+1} staged before next QK
    }

    float* OAp = sh ? OA1 : OA0;
    float* MLp = sh ? ML1 : ML0;
    #pragma unroll
    for (int i=0;i<4;i++){
        float* dst = OAp + (size_t)(q0+qg2*4+i)*D_MOD + h*128 + dg*8;
        *(f4*)dst     = oa[i][0];
        *(f4*)(dst+4) = oa[i][1];
    }
    if (dh == 0 && sg == 0){
        #pragma unroll
        for (int i=0;i<8;i++){
            MLp[(size_t)(q0+qg*8+i)*16 + h*2 + 0] = mstat[i];
            MLp[(size_t)(q0+qg*8+i)*16 + h*2 + 1] = lstat[i];
        }
    }
}

// flash-combine of the two s-halves + the bias-KV token (exact softmax algebra)
__global__ __launch_bounds__(256) void attn_combine(
    const float* __restrict__ Q, const float* __restrict__ kbias,
    const float* __restrict__ vbias,
    const float* __restrict__ OA0, const float* __restrict__ OA1,
    const float* __restrict__ ML0, const float* __restrict__ ML1,
    float* __restrict__ O)
{
    const int row = blockIdx.x, t = threadIdx.x;
    const int h = t >> 5;
    const int cc = t & 31;
    const float qscale = 0.08838834764831845f;
    const f4 qv = *(const f4*)(Q + (size_t)row*D_MOD + h*128 + cc*4);
    const f4 kb = *(const f4*)(kbias + h*128 + cc*4);
    float part = qv.x*kb.x + qv.y*kb.y + qv.z*kb.z + qv.w*kb.w;
    part += __shfl_xor(part,1); part += __shfl_xor(part,2);
    part += __shfl_xor(part,4); part += __shfl_xor(part,8);
    part += __shfl_xor(part,16);
    const float sb = part * qscale;
    const float m0 = ML0[(size_t)row*16 + h*2], l0 = ML0[(size_t)row*16 + h*2 + 1];
    const float m1 = ML1[(size_t)row*16 + h*2], l1 = ML1[(size_t)row*16 + h*2 + 1];
    const float M  = fmaxf(fmaxf(m0, m1), sb);
    const float w0 = __expf(m0 - M), w1 = __expf(m1 - M), wb = __expf(sb - M);
    const float inv = 1.0f / (w0*l0 + w1*l1 + wb);
    const f4 o0 = *(const f4*)(OA0 + (size_t)row*D_MOD + t*4);
    const f4 o1 = *(const f4*)(OA1 + (size_t)row*D_MOD + t*4);
    const f4 vb = *(const f4*)(vbias + h*128 + cc*4);
    f4 o;
    o.x = (o0.x*w0 + o1.x*w1 + vb.x*wb) * inv;
    o.y = (o0.y*w0 + o1.y*w1 + vb.y*wb) * inv;
    o.z = (o0.z*w0 + o1.z*w1 + vb.z*wb) * inv;
    o.w = (o0.w*w0 + o1.w*w1 + vb.w*wb) * inv;
    *(f4*)(O + (size_t)row*D_MOD + t*4) = o;
}

__global__ __launch_bounds__(64) void locate_head(
    const float* __restrict__ mid, const float* __restrict__ W2,
    const float* __restrict__ b2, float* __restrict__ loc_ws,
    float* __restrict__ loc_out)
{
    const int row = blockIdx.x, lane = threadIdx.x;
    const float* m = mid + (size_t)row*512;
    f4 v0 = *(const f4*)(m + lane*8);
    f4 v1 = *(const f4*)(m + lane*8 + 4);
    f4 w0 = *(const f4*)(W2 + lane*8);
    f4 w1 = *(const f4*)(W2 + lane*8 + 4);
    float s = v0.x*w0.x + v0.y*w0.y + v0.z*w0.z + v0.w*w0.w
            + v1.x*w1.x + v1.y*w1.y + v1.z*w1.z + v1.w*w1.w;
    #pragma unroll
    for (int mm=1; mm<64; mm<<=1) s += __shfl_xor(s, mm);
    if (lane==0){
        float z = s + b2[0];
        float l = 1.0f/(1.0f + expf(-z));
        loc_ws[row] = l;
        loc_out[row] = l;
    }
}

__global__ __launch_bounds__(1024) void segscan(
    const float* __restrict__ located, const float* __restrict__ thrp,
    float* __restrict__ out_segid, float* __restrict__ out_segtype,
    float* __restrict__ out_numseg, int* __restrict__ wsi)
{
    __shared__ int clips[2048];
    __shared__ int segid[2048];
    __shared__ int sstart[2049];
    __shared__ int wsum[16];
    const int tid = threadIdx.x;
    const float thr = *thrp;
    for (int t=tid; t<2048; t+=1024) clips[t] = (located[t] > thr) ? 1 : 0;
    __syncthreads();
    const int t0 = tid*2, t1 = t0+1;
    int f0 = (t0==0) ? 0 : (clips[t0]!=clips[t0-1] ? 1 : 0);
    int f1 = (clips[t1]!=clips[t1-1] ? 1 : 0);
    int e0 = f0, e1 = f0+f1;
    const int lane = tid&63, wid = tid>>6;
    int v = e1;
    #pragma unroll
    for (int off=1; off<64; off<<=1){
        int u = __shfl_up(v, off, 64);
        if (lane>=off) v += u;
    }
    if (lane==63) wsum[wid] = v;
    __syncthreads();
    if (tid < 16){
        int w = wsum[tid];
        #pragma unroll
        for (int off=1; off<16; off<<=1){
            int u = __shfl_up(w, off, 16);
            if (tid>=off) w += u;
        }
        wsum[tid] = w;
    }
    __syncthreads();
    int base = (wid>0 ? wsum[wid-1] : 0) + (v - e1);
    segid[t0] = base + e0;
    segid[t1] = base + e1;
    __syncthreads();
    const int ns = segid[2047] + 1;
    for (int t=tid; t<2048; t+=1024){
        if (t==0 || segid[t]!=segid[t-1]) sstart[segid[t]] = t;
    }
    if (tid==0) sstart[ns] = 2048;
    __syncthreads();
    for (int t=tid; t<2048; t+=1024) out_segid[t] = (float)segid[t];
    for (int s=tid; s<2048; s+=1024)
        out_segtype[s] = (s<ns) ? (float)clips[sstart[s]] : -2147483648.0f;
    if (tid==0){ out_numseg[0] = (float)ns; wsi[0] = ns; }
    for (int s=tid; s<=2048; s+=1024) wsi[2+s] = (s<=ns) ? sstart[s] : 0;
}

__global__ __launch_bounds__(256) void segpool(
    const float* __restrict__ V, const float* __restrict__ A,
    const int* __restrict__ wsi, float* __restrict__ out_vid,
    float* __restrict__ out_aud)
{
    const int s = blockIdx.x;
    const int c = threadIdx.x*4;
    const int ns = wsi[0];
    f4 vv; vv.x=0.f; vv.y=0.f; vv.z=0.f; vv.w=0.f;
    f4 av = vv;
    if (s < ns){
        const int st = wsi[2+s], en = wsi[2+s+1];
        for (int r=st; r<en; ++r){
            f4 x = *(const f4*)(V + (size_t)r*D_MOD + c);
            vv.x+=x.x; vv.y+=x.y; vv.z+=x.z; vv.w+=x.w;
            f4 y = *(const f4*)(A + (size_t)r*D_MOD + c);
            av.x+=y.x; av.y+=y.y; av.z+=y.z; av.w+=y.w;
        }
        const float inv = 1.0f/(float)(en-st);
        vv.x*=inv; vv.y*=inv; vv.z*=inv; vv.w*=inv;
        av.x*=inv; av.y*=inv; av.z*=inv; av.w*=inv;
    }
    *(f4*)(out_vid + (size_t)s*D_MOD + c) = vv;
    *(f4*)(out_aud + (size_t)s*D_MOD + c) = av;
}

extern "C" void kernel_launch(void* const* d_in, const int* in_sizes, int n_in,
                              void* d_out, int out_size, void* d_ws, size_t ws_size,
                              hipStream_t stream) {
    (void)in_sizes; (void)n_in; (void)out_size; (void)ws_size;
    const float* video = (const float*)d_in[0];
    const float* audio = (const float*)d_in[1];
    const float* apW1  = (const float*)d_in[2];
    const float* apb1  = (const float*)d_in[3];
    const float* apW2  = (const float*)d_in[4];
    const float* apb2  = (const float*)d_in[5];
    const float* vpW1  = (const float*)d_in[6];
    const float* vpb1  = (const float*)d_in[7];
    const float* vpW2  = (const float*)d_in[8];
    const float* vpb2  = (const float*)d_in[9];
    const float* preg  = (const float*)d_in[10];
    const float* preb  = (const float*)d_in[11];
    const float* bWq   = (const float*)d_in[12];
    const float* bbq   = (const float*)d_in[13];
    const float* bWk   = (const float*)d_in[14];
    const float* bbk   = (const float*)d_in[15];
    const float* bWv   = (const float*)d_in[16];
    const float* bbv   = (const float*)d_in[17];
    const float* bWo   = (const float*)d_in[18];
    const float* bbo   = (const float*)d_in[19];
    const float* bbiask= (const float*)d_in[20];
    const float* bbiasv= (const float*)d_in[21];
    const float* bg1   = (const float*)d_in[22];
    const float* bb1   = (const float*)d_in[23];
    const float* bg2   = (const float*)d_in[24];
    const float* bb2   = (const float*)d_in[25];
    const float* bmW1  = (const float*)d_in[26];
    const float* bmb1  = (const float*)d_in[27];
    const float* bmW2  = (const float*)d_in[28];
    const float* bmb2  = (const float*)d_in[29];
    const float* lhW1  = (const float*)d_in[30];
    const float* lhb1  = (const float*)d_in[31];
    const float* lhW2  = (const float*)d_in[32];
    const float* lhb2  = (const float*)d_in[33];
    const float* thrp  = (const float*)d_in[34];

    float* ws = (float*)d_ws;
    float* V    = ws + 0;
    float* Abuf = ws + 2097152;
    float* X    = ws + 4194304;
    float* H    = ws + 6291456;             // OA1 during attention (dead there)
    float* Q    = ws + 8388608;
    float* Kb   = ws + 10485760;            // 2048*1024
    float* Vb   = ws + 12582912;            // 2048*1024
    float* Obuf = ws + 14680064;            // 2048*1024; OA0 during attention
    float* M4   = ws + 8388608;             // 2048*4096, aliases Q..Obuf
    float* M512 = ws + 16777216;            // 2048*512
    float* LOC  = ws + 17825792;            // 2048
    int*   WSI  = (int*)(ws + 17827840);    // 2051 ints
    float* ML0  = ws + 17829952;            // 2048*8*2
    float* ML1  = ws + 17862720;            // 2048*8*2

    float* out = (float*)d_out;
    float* out_vid     = out + 0;
    float* out_aud     = out + 2097152;
    float* out_loc     = out + 4194304;
    float* out_segid   = out + 4196352;
    float* out_segtype = out + 4198400;
    float* out_numseg  = out + 4200448;

    const dim3 B256(256);
    #define GRID128(M,N) dim3((N)/128,(M)/64)

    // projectors
    gemm128<<<GRID128(2048,512), B256, 0, stream>>>(audio, apW1, apb1, nullptr, M512, 2048,512,128, 1,0);
    gemm128<<<GRID128(2048,1024),B256, 0, stream>>>(M512, apW2, apb2, nullptr, Abuf, 2048,1024,512, 0,0);
    gemm128<<<GRID128(2048,512), B256, 0, stream>>>(video, vpW1, vpb1, nullptr, M512, 2048,512,1024, 1,0);
    gemm128<<<GRID128(2048,1024),B256, 0, stream>>>(M512, vpW2, vpb2, nullptr, V,    2048,1024,512, 0,0);
    lnrow<<<2048, B256, 0, stream>>>(Abuf, preg, preb, X, 1e-6f);

    for (int l=0; l<8; ++l){
        const size_t wo = (size_t)l*1024*1024;
        const size_t bo = (size_t)l*1024;
        const size_t mo1 = (size_t)l*1024*4096;
        lnrow<<<2048, B256, 0, stream>>>(X, bg1+bo, bb1+bo, H, 1e-5f);
        gemm128<<<GRID128(2048,1024),B256,0,stream>>>(H, bWq+wo, bbq+bo, nullptr, Q,  2048,1024,1024, 0,0);
        gemm128<<<GRID128(2048,1024),B256,0,stream>>>(V, bWk+wo, bbk+bo, nullptr, Kb, 2048,1024,1024, 0,0);
        gemm128<<<GRID128(2048,1024),B256,0,stream>>>(V, bWv+wo, bbv+bo, nullptr, Vb, 2048,1024,1024, 0,0);
        attn128s<<<256, dim3(512), 0, stream>>>(Q, Kb, Vb, Obuf, H, ML0, ML1);
        attn_combine<<<2048, B256, 0, stream>>>(Q, bbiask+bo, bbiasv+bo, Obuf, H, ML0, ML1, Obuf);
        gemm128<<<GRID128(2048,1024),B256,0,stream>>>(Obuf, bWo+wo, bbo+bo, X, X, 2048,1024,1024, 0,1);
        lnrow<<<2048, B256, 0, stream>>>(X, bg2+bo, bb2+bo, H, 1e-5f);
        gemm128<<<GRID128(2048,4096),B256,0,stream>>>(H, bmW1+mo1, bmb1+(size_t)l*4096, nullptr, M4, 2048,4096,1024, 2,0);
        gemm128<<<GRID128(2048,1024),B256,0,stream>>>(M4, bmW2+mo1, bmb2+bo, X, X, 2048,1024,4096, 0,1);
    }

    gemm128<<<GRID128(2048,512), B256, 0, stream>>>(X, lhW1, lhb1, nullptr, M512, 2048,512,1024, 1,0);
    locate_head<<<2048, dim3(64), 0, stream>>>(M512, lhW2, lhb2, LOC, out_loc);
    segscan<<<1, dim3(1024), 0, stream>>>(LOC, thrp, out_segid, out_segtype, out_numseg, WSI);
    segpool<<<2048, B256, 0, stream>>>(V, Abuf, WSI, out_vid, out_aud);
}

// Round 7
// 8540.524 us; speedup vs baseline: 9.0479x; 1.0924x over previous
//
#include <hip/hip_runtime.h>
#include <math.h>

typedef float4 f4;

#define T_SEQ 2048
#define D_MOD 1024

__device__ __forceinline__ float gelu_f(float x){
    float u = 0.7978845608028654f*(x + 0.044715f*x*x*x);
    return 0.5f*x*(1.0f + tanhf(u));
}

// C[M,N] = act(A[M,K] @ W[K,N] + bias) (+ res)
// 64x128 tile, 512 threads, intra-block split-K x2:
//   waves 0-3 (t=tid&255, khalf=0) accumulate K[0..K/2), waves 4-7 K[K/2..K).
//   Deterministic combine: acc = accK0 + accK1 elementwise (fixed order), then
//   +bias, act, +res — same epilogue order as before.
// Ws stores chunk c of each row at slot (c>>1)|((c&1)<<4): wA reads slots 0..15,
// wB slots 16..31 -> 16B-stride across lanes -> 2-way bank alias (free).
__global__ __launch_bounds__(512) void gemm128k2(
    const float* __restrict__ A, const float* __restrict__ W,
    const float* __restrict__ bias, const float* __restrict__ res,
    float* __restrict__ C, int M, int N, int K, int act, int hasres)
{
    __shared__ float As[2][32][68];
    __shared__ float Ws[2][32][132];
    const int tid = threadIdx.x;
    const int kh = tid >> 8;            // K-half
    const int t  = tid & 255;
    const int row0 = blockIdx.y*64, col0 = blockIdx.x*128;
    const int ty = t>>4, tx = t&15;
    const int am = t>>2, ak = (t&3)*8;
    const int wk = t>>3, u  = t&7;      // W: row wk, chunk group u (cols u*16..+15)
    const int K2 = K >> 1;
    const float* Ap = A + (size_t)(row0+am)*K + kh*K2 + ak;
    const float* Wp = W + (size_t)(kh*K2 + wk)*N + col0 + u*16;
    float* Wrow = &Ws[kh][wk][0];

    f4 a0,a1,w0,w1,w2,w3;
    a0 = *(const f4*)(Ap);
    a1 = *(const f4*)(Ap + 4);
    w0 = *(const f4*)(Wp);
    w1 = *(const f4*)(Wp + 4);
    w2 = *(const f4*)(Wp + 8);
    w3 = *(const f4*)(Wp + 12);
    As[kh][ak+0][am]=a0.x; As[kh][ak+1][am]=a0.y; As[kh][ak+2][am]=a0.z; As[kh][ak+3][am]=a0.w;
    As[kh][ak+4][am]=a1.x; As[kh][ak+5][am]=a1.y; As[kh][ak+6][am]=a1.z; As[kh][ak+7][am]=a1.w;
    // permuted: slot 2u <- chunk 4u (w0); slot 2u+1 <- chunk 4u+2 (w2);
    //           slot 16+2u <- chunk 4u+1 (w1); slot 16+2u+1 <- chunk 4u+3 (w3)
    *(f4*)(Wrow + 8*u)      = w0;
    *(f4*)(Wrow + 8*u + 4)  = w2;
    *(f4*)(Wrow + 64 + 8*u)     = w1;
    *(f4*)(Wrow + 64 + 8*u + 4) = w3;
    __syncthreads();

    float acc[4][8];
    #pragma unroll
    for (int i=0;i<4;i++){
        #pragma unroll
        for (int j=0;j<8;j++) acc[i][j]=0.f;
    }

    int k0 = 0;
    while (true){
        const int kn = k0 + 32;
        const bool more = kn < K2;
        if (more){
            a0 = *(const f4*)(Ap + kn);
            a1 = *(const f4*)(Ap + kn + 4);
            w0 = *(const f4*)(Wp + (size_t)kn*N);
            w1 = *(const f4*)(Wp + (size_t)kn*N + 4);
            w2 = *(const f4*)(Wp + (size_t)kn*N + 8);
            w3 = *(const f4*)(Wp + (size_t)kn*N + 12);
        }
        #pragma unroll
        for (int kk=0;kk<32;kk++){
            f4 a  = *(const f4*)&As[kh][kk][ty*4];
            f4 wA = *(const f4*)&Ws[kh][kk][tx*4];        // slot tx = cols 8tx..+3
            f4 wB = *(const f4*)&Ws[kh][kk][64 + tx*4];   // slot 16+tx = cols 8tx+4..+7
            float ar[4] = {a.x,a.y,a.z,a.w};
            #pragma unroll
            for (int i=0;i<4;i++){
                acc[i][0] += ar[i]*wA.x;
                acc[i][1] += ar[i]*wA.y;
                acc[i][2] += ar[i]*wA.z;
                acc[i][3] += ar[i]*wA.w;
                acc[i][4] += ar[i]*wB.x;
                acc[i][5] += ar[i]*wB.y;
                acc[i][6] += ar[i]*wB.z;
                acc[i][7] += ar[i]*wB.w;
            }
        }
        __syncthreads();
        if (!more) break;
        As[kh][ak+0][am]=a0.x; As[kh][ak+1][am]=a0.y; As[kh][ak+2][am]=a0.z; As[kh][ak+3][am]=a0.w;
        As[kh][ak+4][am]=a1.x; As[kh][ak+5][am]=a1.y; As[kh][ak+6][am]=a1.z; As[kh][ak+7][am]=a1.w;
        *(f4*)(Wrow + 8*u)      = w0;
        *(f4*)(Wrow + 8*u + 4)  = w2;
        *(f4*)(Wrow + 64 + 8*u)     = w1;
        *(f4*)(Wrow + 64 + 8*u + 4) = w3;
        __syncthreads();
        k0 = kn;
    }

    // combine halves through LDS scratch (overlaid on Ws; layout [8 f4][256 thr])
    float* cs = &Ws[0][0][0];
    if (kh == 1){
        #pragma unroll
        for (int i=0;i<4;i++){
            #pragma unroll
            for (int b=0;b<2;b++){
                f4 p;
                p.x=acc[i][b*4+0]; p.y=acc[i][b*4+1]; p.z=acc[i][b*4+2]; p.w=acc[i][b*4+3];
                *(f4*)(cs + 4*(((i<<1)|b)*256 + t)) = p;
            }
        }
    }
    __syncthreads();
    if (kh == 0){
        #pragma unroll
        for (int i=0;i<4;i++){
            #pragma unroll
            for (int b=0;b<2;b++){
                const f4 p = *(const f4*)(cs + 4*(((i<<1)|b)*256 + t));
                acc[i][b*4+0]+=p.x; acc[i][b*4+1]+=p.y; acc[i][b*4+2]+=p.z; acc[i][b*4+3]+=p.w;
            }
        }
        #pragma unroll
        for (int i=0;i<4;i++){
            const int r = row0 + ty*4 + i;
            #pragma unroll
            for (int half=0; half<2; ++half){
                const int cb = col0 + tx*8 + half*4;
                f4 bv = *(const f4*)(bias + cb);
                float t0 = acc[i][half*4+0] + bv.x;
                float t1 = acc[i][half*4+1] + bv.y;
                float t2 = acc[i][half*4+2] + bv.z;
                float t3 = acc[i][half*4+3] + bv.w;
                if (act==1){ t0=fmaxf(t0,0.f); t1=fmaxf(t1,0.f); t2=fmaxf(t2,0.f); t3=fmaxf(t3,0.f); }
                else if (act==2){ t0=gelu_f(t0); t1=gelu_f(t1); t2=gelu_f(t2); t3=gelu_f(t3); }
                if (hasres){
                    f4 rv = *(const f4*)(res + (size_t)r*N + cb);
                    t0+=rv.x; t1+=rv.y; t2+=rv.z; t3+=rv.w;
                }
                f4 o; o.x=t0; o.y=t1; o.z=t2; o.w=t3;
                *(f4*)(C + (size_t)r*N + cb) = o;
            }
        }
    }
}

__global__ __launch_bounds__(256) void lnrow(
    const float* __restrict__ X, const float* __restrict__ g,
    const float* __restrict__ b, float* __restrict__ out, float eps)
{
    __shared__ float red[4];
    const int row = blockIdx.x, tid = threadIdx.x;
    const float* xp = X + (size_t)row*D_MOD;
    f4 xv = *(const f4*)(xp + tid*4);
    float s = xv.x+xv.y+xv.z+xv.w;
    #pragma unroll
    for (int m=1;m<64;m<<=1) s += __shfl_xor(s, m);
    const int wid = tid>>6, lane = tid&63;
    if (lane==0) red[wid]=s;
    __syncthreads();
    float mean = (red[0]+red[1]+red[2]+red[3]) * (1.0f/1024.0f);
    __syncthreads();
    float d0=xv.x-mean, d1=xv.y-mean, d2=xv.z-mean, d3=xv.w-mean;
    float q = d0*d0+d1*d1+d2*d2+d3*d3;
    #pragma unroll
    for (int m=1;m<64;m<<=1) q += __shfl_xor(q, m);
    if (lane==0) red[wid]=q;
    __syncthreads();
    float var = (red[0]+red[1]+red[2]+red[3]) * (1.0f/1024.0f);
    float inv = rsqrtf(var + eps);
    f4 gv = *(const f4*)(g + tid*4);
    f4 bv = *(const f4*)(b + tid*4);
    f4 o;
    o.x = d0*inv*gv.x + bv.x;
    o.y = d1*inv*gv.y + bv.y;
    o.z = d2*inv*gv.z + bv.z;
    o.w = d3*inv*gv.w + bv.w;
    *(f4*)(out + (size_t)row*D_MOD + tid*4) = o;
}

// flash attention, QBLK=128, s-split=2, 512 threads (8 waves, 2/SIMD).
#define KS4(r) ((f4*)&ks[r][0])
#define VS4(r) ((f4*)&vs[r][0])
#define QS4(r) ((f4*)&qs[r][0])
__global__ __launch_bounds__(512,1) void attn128s(
    const float* __restrict__ Q, const float* __restrict__ Kb,
    const float* __restrict__ Vb,
    float* __restrict__ OA0, float* __restrict__ OA1,
    float* __restrict__ ML0, float* __restrict__ ML1)
{
    __shared__ float qs[128][132];
    __shared__ float ks[64][132];   // K tile; P[s][q] alias between b1..b3
    __shared__ float vs[64][132];
    __shared__ float scs[128];
    const int tid = threadIdx.x;
    const int h  = blockIdx.x & 7;
    const int sh = (blockIdx.x >> 3) & 1;
    const int q0 = (blockIdx.x >> 4) * 128;
    const int dh = tid & 1;
    const int sg = (tid >> 1) & 15;
    const int qg = tid >> 5;
    const int qg2 = tid >> 4;
    const int dg  = tid & 15;
    const int c4 = tid & 31, rb = tid >> 5;
    const int sbase = sh * 1024;
    const float qscale = 0.08838834764831845f; // 1/sqrt(128)

    f4 kr[4], vr[4];
    #pragma unroll
    for (int j=0;j<4;j++){
        const int r = rb + 16*j;
        kr[j] = *(const f4*)(Kb + (size_t)(sbase+r)*D_MOD + h*128 + c4*4);
        vr[j] = *(const f4*)(Vb + (size_t)(sbase+r)*D_MOD + h*128 + c4*4);
    }
    #pragma unroll
    for (int kq=0;kq<8;kq++){
        const int i = tid + kq*512;
        const int r = i>>5, cc = i&31;
        f4 v = *(const f4*)(Q + (size_t)(q0+r)*D_MOD + h*128 + cc*4);
        v.x*=qscale; v.y*=qscale; v.z*=qscale; v.w*=qscale;
        QS4(r)[cc ^ ((r>>2)&7)] = v;
    }
    #pragma unroll
    for (int j=0;j<4;j++){
        const int r = rb + 16*j;
        const int key = (r>>2)&7;
        KS4(r)[c4 ^ key] = kr[j];
        VS4(r)[c4 ^ key] = vr[j];
    }
    #pragma unroll
    for (int j=0;j<4;j++){
        const int r = rb + 16*j;
        kr[j] = *(const f4*)(Kb + (size_t)(sbase+64+r)*D_MOD + h*128 + c4*4);
        vr[j] = *(const f4*)(Vb + (size_t)(sbase+64+r)*D_MOD + h*128 + c4*4);
    }
    __syncthreads();

    float mstat[8], lstat[8];
    f4 oa[4][2];
    #pragma unroll
    for (int i=0;i<8;i++){ mstat[i] = -__builtin_inff(); lstat[i] = 0.f; }
    #pragma unroll
    for (int i=0;i<4;i++){
        #pragma unroll
        for (int b=0;b<2;b++){ oa[i][b].x=0.f; oa[i][b].y=0.f; oa[i][b].z=0.f; oa[i][b].w=0.f; }
    }

    for (int t=0; t<16; ++t){
        // ---- QK^T: acc[8q][4s] over this thread's 64-d half ----
        float acc[8][4];
        #pragma unroll
        for (int i=0;i<8;i++){
            #pragma unroll
            for (int j=0;j<4;j++) acc[i][j]=0.f;
        }
        #pragma unroll
        for (int c=0;c<16;c++){
            const int ch = dh*16 + c;
            f4 kv[4];
            #pragma unroll
            for (int j=0;j<4;j++) kv[j] = KS4(sg*4+j)[ch ^ (sg&7)];
            #pragma unroll
            for (int i=0;i<8;i++){
                const f4 qv = QS4(qg*8+i)[ch ^ ((qg*2+(i>>2))&7)];
                #pragma unroll
                for (int j=0;j<4;j++)
                    acc[i][j] += qv.x*kv[j].x + qv.y*kv[j].y + qv.z*kv[j].z + qv.w*kv[j].w;
            }
        }
        __syncthreads();   // b1: ks region free (K_t consumed)

        // ---- combine d-halves + online softmax ----
        float scarr[8];
        #pragma unroll
        for (int i=0;i<8;i++){
            #pragma unroll
            for (int j=0;j<4;j++) acc[i][j] += __shfl_xor(acc[i][j], 1);
            float tm = fmaxf(fmaxf(acc[i][0],acc[i][1]), fmaxf(acc[i][2],acc[i][3]));
            tm = fmaxf(tm, __shfl_xor(tm,2));
            tm = fmaxf(tm, __shfl_xor(tm,4));
            tm = fmaxf(tm, __shfl_xor(tm,8));
            tm = fmaxf(tm, __shfl_xor(tm,16));
            const float mn = fmaxf(mstat[i], tm);
            const float sc = __expf(mstat[i] - mn);
            float rs = 0.f;
            #pragma unroll
            for (int j=0;j<4;j++){
                const float p = __expf(acc[i][j] - mn);
                acc[i][j] = p; rs += p;
            }
            rs += __shfl_xor(rs,2); rs += __shfl_xor(rs,4);
            rs += __shfl_xor(rs,8); rs += __shfl_xor(rs,16);
            lstat[i] = lstat[i]*sc + rs;
            mstat[i] = mn;
            scarr[i] = sc;
        }
        // write P (transposed [s][q]) into ks region; write per-q scales
        if (dh == 0){
            #pragma unroll
            for (int j=0;j<4;j++){
                const int s = sg*4 + j;
                f4 pw0, pw1;
                pw0.x=acc[0][j]; pw0.y=acc[1][j]; pw0.z=acc[2][j]; pw0.w=acc[3][j];
                pw1.x=acc[4][j]; pw1.y=acc[5][j]; pw1.z=acc[6][j]; pw1.w=acc[7][j];
                KS4(s)[2*qg]   = pw0;
                KS4(s)[2*qg+1] = pw1;
            }
            if (sg == 0){
                f4 s0, s1;
                s0.x=scarr[0]; s0.y=scarr[1]; s0.z=scarr[2]; s0.w=scarr[3];
                s1.x=scarr[4]; s1.y=scarr[5]; s1.z=scarr[6]; s1.w=scarr[7];
                ((f4*)scs)[2*qg]   = s0;
                ((f4*)scs)[2*qg+1] = s1;
            }
        }
        __syncthreads();   // b2: P + scales ready

        // ---- PV: thread owns 4 q rows x 8 d; iterate all 64 s ----
        {
            const f4 scf = ((const f4*)scs)[qg2];
            #pragma unroll
            for (int b=0;b<2;b++){
                oa[0][b].x*=scf.x; oa[0][b].y*=scf.x; oa[0][b].z*=scf.x; oa[0][b].w*=scf.x;
                oa[1][b].x*=scf.y; oa[1][b].y*=scf.y; oa[1][b].z*=scf.y; oa[1][b].w*=scf.y;
                oa[2][b].x*=scf.z; oa[2][b].y*=scf.z; oa[2][b].z*=scf.z; oa[2][b].w*=scf.z;
                oa[3][b].x*=scf.w; oa[3][b].y*=scf.w; oa[3][b].z*=scf.w; oa[3][b].w*=scf.w;
            }
        }
        #pragma unroll 4
        for (int s=0; s<64; ++s){
            const int vkey = (s>>2)&7;
            const f4 pv = KS4(s)[qg2];
            const f4 v0 = VS4(s)[(2*dg)   ^ vkey];
            const f4 v1 = VS4(s)[(2*dg+1) ^ vkey];
            oa[0][0].x+=pv.x*v0.x; oa[0][0].y+=pv.x*v0.y; oa[0][0].z+=pv.x*v0.z; oa[0][0].w+=pv.x*v0.w;
            oa[0][1].x+=pv.x*v1.x; oa[0][1].y+=pv.x*v1.y; oa[0][1].z+=pv.x*v1.z; oa[0][1].w+=pv.x*v1.w;
            oa[1][0].x+=pv.y*v0.x; oa[1][0].y+=pv.y*v0.y; oa[1][0].z+=pv.y*v0.z; oa[1][0].w+=pv.y*v0.w;
            oa[1][1].x+=pv.y*v1.x; oa[1][1].y+=pv.y*v1.y; oa[1][1].z+=pv.y*v1.z; oa[1][1].w+=pv.y*v1.w;
            oa[2][0].x+=pv.z*v0.x; oa[2][0].y+=pv.z*v0.y; oa[2][0].z+=pv.z*v0.z; oa[2][0].w+=pv.z*v0.w;
            oa[2][1].x+=pv.z*v1.x; oa[2][1].y+=pv.z*v1.y; oa[2][1].z+=pv.z*v1.z; oa[2][1].w+=pv.z*v1.w;
            oa[3][0].x+=pv.w*v0.x; oa[3][0].y+=pv.w*v0.y; oa[3][0].z+=pv.w*v0.z; oa[3][0].w+=pv.w*v0.w;
            oa[3][1].x+=pv.w*v1.x; oa[3][1].y+=pv.w*v1.y; oa[3][1].z+=pv.w*v1.z; oa[3][1].w+=pv.w*v1.w;
        }
        __syncthreads();   // b3: ks (P) and vs (V_t) free

        if (t < 15){
            #pragma unroll
            for (int j=0;j<4;j++){
                const int r = rb + 16*j;
                const int key = (r>>2)&7;
                KS4(r)[c4 ^ key] = kr[j];
                VS4(r)[c4 ^ key] = vr[j];
            }
            if (t < 14){
                #pragma unroll
                for (int j=0;j<4;j++){
                    const int gr = sbase + (t+2)*64 + rb + 16*j;
                    kr[j] = *(const f4*)(Kb + (size_t)gr*D_MOD + h*128 + c4*4);
                    vr[j] = *(const f4*)(Vb + (size_t)gr*D_MOD + h*128 + c4*4);
                }
            }
        }
        __syncthreads();   // b4: K_{t+1}/V_{t+1} staged before next QK
    }

    float* OAp = sh ? OA1 : OA0;
    float* MLp = sh ? ML1 : ML0;
    #pragma unroll
    for (int i=0;i<4;i++){
        float* dst = OAp + (size_t)(q0+qg2*4+i)*D_MOD + h*128 + dg*8;
        *(f4*)dst     = oa[i][0];
        *(f4*)(dst+4) = oa[i][1];
    }
    if (dh == 0 && sg == 0){
        #pragma unroll
        for (int i=0;i<8;i++){
            MLp[(size_t)(q0+qg*8+i)*16 + h*2 + 0] = mstat[i];
            MLp[(size_t)(q0+qg*8+i)*16 + h*2 + 1] = lstat[i];
        }
    }
}

// flash-combine of the two s-halves + the bias-KV token (exact softmax algebra)
__global__ __launch_bounds__(256) void attn_combine(
    const float* __restrict__ Q, const float* __restrict__ kbias,
    const float* __restrict__ vbias,
    const float* __restrict__ OA0, const float* __restrict__ OA1,
    const float* __restrict__ ML0, const float* __restrict__ ML1,
    float* __restrict__ O)
{
    const int row = blockIdx.x, t = threadIdx.x;
    const int h = t >> 5;
    const int cc = t & 31;
    const float qscale = 0.08838834764831845f;
    const f4 qv = *(const f4*)(Q + (size_t)row*D_MOD + h*128 + cc*4);
    const f4 kb = *(const f4*)(kbias + h*128 + cc*4);
    float part = qv.x*kb.x + qv.y*kb.y + qv.z*kb.z + qv.w*kb.w;
    part += __shfl_xor(part,1); part += __shfl_xor(part,2);
    part += __shfl_xor(part,4); part += __shfl_xor(part,8);
    part += __shfl_xor(part,16);
    const float sb = part * qscale;
    const float m0 = ML0[(size_t)row*16 + h*2], l0 = ML0[(size_t)row*16 + h*2 + 1];
    const float m1 = ML1[(size_t)row*16 + h*2], l1 = ML1[(size_t)row*16 + h*2 + 1];
    const float M  = fmaxf(fmaxf(m0, m1), sb);
    const float w0 = __expf(m0 - M), w1 = __expf(m1 - M), wb = __expf(sb - M);
    const float inv = 1.0f / (w0*l0 + w1*l1 + wb);
    const f4 o0 = *(const f4*)(OA0 + (size_t)row*D_MOD + t*4);
    const f4 o1 = *(const f4*)(OA1 + (size_t)row*D_MOD + t*4);
    const f4 vb = *(const f4*)(vbias + h*128 + cc*4);
    f4 o;
    o.x = (o0.x*w0 + o1.x*w1 + vb.x*wb) * inv;
    o.y = (o0.y*w0 + o1.y*w1 + vb.y*wb) * inv;
    o.z = (o0.z*w0 + o1.z*w1 + vb.z*wb) * inv;
    o.w = (o0.w*w0 + o1.w*w1 + vb.w*wb) * inv;
    *(f4*)(O + (size_t)row*D_MOD + t*4) = o;
}

__global__ __launch_bounds__(64) void locate_head(
    const float* __restrict__ mid, const float* __restrict__ W2,
    const float* __restrict__ b2, float* __restrict__ loc_ws,
    float* __restrict__ loc_out)
{
    const int row = blockIdx.x, lane = threadIdx.x;
    const float* m = mid + (size_t)row*512;
    f4 v0 = *(const f4*)(m + lane*8);
    f4 v1 = *(const f4*)(m + lane*8 + 4);
    f4 w0 = *(const f4*)(W2 + lane*8);
    f4 w1 = *(const f4*)(W2 + lane*8 + 4);
    float s = v0.x*w0.x + v0.y*w0.y + v0.z*w0.z + v0.w*w0.w
            + v1.x*w1.x + v1.y*w1.y + v1.z*w1.z + v1.w*w1.w;
    #pragma unroll
    for (int mm=1; mm<64; mm<<=1) s += __shfl_xor(s, mm);
    if (lane==0){
        float z = s + b2[0];
        float l = 1.0f/(1.0f + expf(-z));
        loc_ws[row] = l;
        loc_out[row] = l;
    }
}

__global__ __launch_bounds__(1024) void segscan(
    const float* __restrict__ located, const float* __restrict__ thrp,
    float* __restrict__ out_segid, float* __restrict__ out_segtype,
    float* __restrict__ out_numseg, int* __restrict__ wsi)
{
    __shared__ int clips[2048];
    __shared__ int segid[2048];
    __shared__ int sstart[2049];
    __shared__ int wsum[16];
    const int tid = threadIdx.x;
    const float thr = *thrp;
    for (int t=tid; t<2048; t+=1024) clips[t] = (located[t] > thr) ? 1 : 0;
    __syncthreads();
    const int t0 = tid*2, t1 = t0+1;
    int f0 = (t0==0) ? 0 : (clips[t0]!=clips[t0-1] ? 1 : 0);
    int f1 = (clips[t1]!=clips[t1-1] ? 1 : 0);
    int e0 = f0, e1 = f0+f1;
    const int lane = tid&63, wid = tid>>6;
    int v = e1;
    #pragma unroll
    for (int off=1; off<64; off<<=1){
        int u = __shfl_up(v, off, 64);
        if (lane>=off) v += u;
    }
    if (lane==63) wsum[wid] = v;
    __syncthreads();
    if (tid < 16){
        int w = wsum[tid];
        #pragma unroll
        for (int off=1; off<16; off<<=1){
            int u = __shfl_up(w, off, 16);
            if (tid>=off) w += u;
        }
        wsum[tid] = w;
    }
    __syncthreads();
    int base = (wid>0 ? wsum[wid-1] : 0) + (v - e1);
    segid[t0] = base + e0;
    segid[t1] = base + e1;
    __syncthreads();
    const int ns = segid[2047] + 1;
    for (int t=tid; t<2048; t+=1024){
        if (t==0 || segid[t]!=segid[t-1]) sstart[segid[t]] = t;
    }
    if (tid==0) sstart[ns] = 2048;
    __syncthreads();
    for (int t=tid; t<2048; t+=1024) out_segid[t] = (float)segid[t];
    for (int s=tid; s<2048; s+=1024)
        out_segtype[s] = (s<ns) ? (float)clips[sstart[s]] : -2147483648.0f;
    if (tid==0){ out_numseg[0] = (float)ns; wsi[0] = ns; }
    for (int s=tid; s<=2048; s+=1024) wsi[2+s] = (s<=ns) ? sstart[s] : 0;
}

__global__ __launch_bounds__(256) void segpool(
    const float* __restrict__ V, const float* __restrict__ A,
    const int* __restrict__ wsi, float* __restrict__ out_vid,
    float* __restrict__ out_aud)
{
    const int s = blockIdx.x;
    const int c = threadIdx.x*4;
    const int ns = wsi[0];
    f4 vv; vv.x=0.f; vv.y=0.f; vv.z=0.f; vv.w=0.f;
    f4 av = vv;
    if (s < ns){
        const int st = wsi[2+s], en = wsi[2+s+1];
        for (int r=st; r<en; ++r){
            f4 x = *(const f4*)(V + (size_t)r*D_MOD + c);
            vv.x+=x.x; vv.y+=x.y; vv.z+=x.z; vv.w+=x.w;
            f4 y = *(const f4*)(A + (size_t)r*D_MOD + c);
            av.x+=y.x; av.y+=y.y; av.z+=y.z; av.w+=y.w;
        }
        const float inv = 1.0f/(float)(en-st);
        vv.x*=inv; vv.y*=inv; vv.z*=inv; vv.w*=inv;
        av.x*=inv; av.y*=inv; av.z*=inv; av.w*=inv;
    }
    *(f4*)(out_vid + (size_t)s*D_MOD + c) = vv;
    *(f4*)(out_aud + (size_t)s*D_MOD + c) = av;
}

extern "C" void kernel_launch(void* const* d_in, const int* in_sizes, int n_in,
                              void* d_out, int out_size, void* d_ws, size_t ws_size,
                              hipStream_t stream) {
    (void)in_sizes; (void)n_in; (void)out_size; (void)ws_size;
    const float* video = (const float*)d_in[0];
    const float* audio = (const float*)d_in[1];
    const float* apW1  = (const float*)d_in[2];
    const float* apb1  = (const float*)d_in[3];
    const float* apW2  = (const float*)d_in[4];
    const float* apb2  = (const float*)d_in[5];
    const float* vpW1  = (const float*)d_in[6];
    const float* vpb1  = (const float*)d_in[7];
    const float* vpW2  = (const float*)d_in[8];
    const float* vpb2  = (const float*)d_in[9];
    const float* preg  = (const float*)d_in[10];
    const float* preb  = (const float*)d_in[11];
    const float* bWq   = (const float*)d_in[12];
    const float* bbq   = (const float*)d_in[13];
    const float* bWk   = (const float*)d_in[14];
    const float* bbk   = (const float*)d_in[15];
    const float* bWv   = (const float*)d_in[16];
    const float* bbv   = (const float*)d_in[17];
    const float* bWo   = (const float*)d_in[18];
    const float* bbo   = (const float*)d_in[19];
    const float* bbiask= (const float*)d_in[20];
    const float* bbiasv= (const float*)d_in[21];
    const float* bg1   = (const float*)d_in[22];
    const float* bb1   = (const float*)d_in[23];
    const float* bg2   = (const float*)d_in[24];
    const float* bb2   = (const float*)d_in[25];
    const float* bmW1  = (const float*)d_in[26];
    const float* bmb1  = (const float*)d_in[27];
    const float* bmW2  = (const float*)d_in[28];
    const float* bmb2  = (const float*)d_in[29];
    const float* lhW1  = (const float*)d_in[30];
    const float* lhb1  = (const float*)d_in[31];
    const float* lhW2  = (const float*)d_in[32];
    const float* lhb2  = (const float*)d_in[33];
    const float* thrp  = (const float*)d_in[34];

    float* ws = (float*)d_ws;
    float* V    = ws + 0;
    float* Abuf = ws + 2097152;
    float* X    = ws + 4194304;
    float* H    = ws + 6291456;             // OA1 during attention (dead there)
    float* Q    = ws + 8388608;
    float* Kb   = ws + 10485760;            // 2048*1024
    float* Vb   = ws + 12582912;            // 2048*1024
    float* Obuf = ws + 14680064;            // 2048*1024; OA0 during attention
    float* M4   = ws + 8388608;             // 2048*4096, aliases Q..Obuf
    float* M512 = ws + 16777216;            // 2048*512
    float* LOC  = ws + 17825792;            // 2048
    int*   WSI  = (int*)(ws + 17827840);    // 2051 ints
    float* ML0  = ws + 17829952;            // 2048*8*2
    float* ML1  = ws + 17862720;            // 2048*8*2

    float* out = (float*)d_out;
    float* out_vid     = out + 0;
    float* out_aud     = out + 2097152;
    float* out_loc     = out + 4194304;
    float* out_segid   = out + 4196352;
    float* out_segtype = out + 4198400;
    float* out_numseg  = out + 4200448;

    const dim3 B512(512);
    const dim3 B256(256);
    #define GRID128(M,N) dim3((N)/128,(M)/64)

    // projectors
    gemm128k2<<<GRID128(2048,512), B512, 0, stream>>>(audio, apW1, apb1, nullptr, M512, 2048,512,128, 1,0);
    gemm128k2<<<GRID128(2048,1024),B512, 0, stream>>>(M512, apW2, apb2, nullptr, Abuf, 2048,1024,512, 0,0);
    gemm128k2<<<GRID128(2048,512), B512, 0, stream>>>(video, vpW1, vpb1, nullptr, M512, 2048,512,1024, 1,0);
    gemm128k2<<<GRID128(2048,1024),B512, 0, stream>>>(M512, vpW2, vpb2, nullptr, V,    2048,1024,512, 0,0);
    lnrow<<<2048, B256, 0, stream>>>(Abuf, preg, preb, X, 1e-6f);

    for (int l=0; l<8; ++l){
        const size_t wo = (size_t)l*1024*1024;
        const size_t bo = (size_t)l*1024;
        const size_t mo1 = (size_t)l*1024*4096;
        lnrow<<<2048, B256, 0, stream>>>(X, bg1+bo, bb1+bo, H, 1e-5f);
        gemm128k2<<<GRID128(2048,1024),B512,0,stream>>>(H, bWq+wo, bbq+bo, nullptr, Q,  2048,1024,1024, 0,0);
        gemm128k2<<<GRID128(2048,1024),B512,0,stream>>>(V, bWk+wo, bbk+bo, nullptr, Kb, 2048,1024,1024, 0,0);
        gemm128k2<<<GRID128(2048,1024),B512,0,stream>>>(V, bWv+wo, bbv+bo, nullptr, Vb, 2048,1024,1024, 0,0);
        attn128s<<<256, B512, 0, stream>>>(Q, Kb, Vb, Obuf, H, ML0, ML1);
        attn_combine<<<2048, B256, 0, stream>>>(Q, bbiask+bo, bbiasv+bo, Obuf, H, ML0, ML1, Obuf);
        gemm128k2<<<GRID128(2048,1024),B512,0,stream>>>(Obuf, bWo+wo, bbo+bo, X, X, 2048,1024,1024, 0,1);
        lnrow<<<2048, B256, 0, stream>>>(X, bg2+bo, bb2+bo, H, 1e-5f);
        gemm128k2<<<GRID128(2048,4096),B512,0,stream>>>(H, bmW1+mo1, bmb1+(size_t)l*4096, nullptr, M4, 2048,4096,1024, 2,0);
        gemm128k2<<<GRID128(2048,1024),B512,0,stream>>>(M4, bmW2+mo1, bmb2+bo, X, X, 2048,1024,4096, 0,1);
    }

    gemm128k2<<<GRID128(2048,512), B512, 0, stream>>>(X, lhW1, lhb1, nullptr, M512, 2048,512,1024, 1,0);
    locate_head<<<2048, dim3(64), 0, stream>>>(M512, lhW2, lhb2, LOC, out_loc);
    segscan<<<1, dim3(1024), 0, stream>>>(LOC, thrp, out_segid, out_segtype, out_numseg, WSI);
    segpool<<<2048, B256, 0, stream>>>(V, Abuf, WSI, out_vid, out_aud);
}

// Round 8
// 8218.166 us; speedup vs baseline: 9.4028x; 1.0392x over previous
//
#include <hip/hip_runtime.h>
#include <math.h>

typedef float4 f4;

#define T_SEQ 2048
#define D_MOD 1024

__device__ __forceinline__ float gelu_f(float x){
    float u = 0.7978845608028654f*(x + 0.044715f*x*x*x);
    return 0.5f*x*(1.0f + tanhf(u));
}

// C[M,N] = act(A[M,K] @ W[K,N] + bias) (+ res)
// 64x128 tile, 512 threads, intra-block split-K x2 (deterministic combine).
__global__ __launch_bounds__(512) void gemm128k2(
    const float* __restrict__ A, const float* __restrict__ W,
    const float* __restrict__ bias, const float* __restrict__ res,
    float* __restrict__ C, int M, int N, int K, int act, int hasres)
{
    __shared__ float As[2][32][68];
    __shared__ float Ws[2][32][132];
    const int tid = threadIdx.x;
    const int kh = tid >> 8;            // K-half
    const int t  = tid & 255;
    const int row0 = blockIdx.y*64, col0 = blockIdx.x*128;
    const int ty = t>>4, tx = t&15;
    const int am = t>>2, ak = (t&3)*8;
    const int wk = t>>3, u  = t&7;
    const int K2 = K >> 1;
    const float* Ap = A + (size_t)(row0+am)*K + kh*K2 + ak;
    const float* Wp = W + (size_t)(kh*K2 + wk)*N + col0 + u*16;
    float* Wrow = &Ws[kh][wk][0];

    f4 a0,a1,w0,w1,w2,w3;
    a0 = *(const f4*)(Ap);
    a1 = *(const f4*)(Ap + 4);
    w0 = *(const f4*)(Wp);
    w1 = *(const f4*)(Wp + 4);
    w2 = *(const f4*)(Wp + 8);
    w3 = *(const f4*)(Wp + 12);
    As[kh][ak+0][am]=a0.x; As[kh][ak+1][am]=a0.y; As[kh][ak+2][am]=a0.z; As[kh][ak+3][am]=a0.w;
    As[kh][ak+4][am]=a1.x; As[kh][ak+5][am]=a1.y; As[kh][ak+6][am]=a1.z; As[kh][ak+7][am]=a1.w;
    *(f4*)(Wrow + 8*u)      = w0;
    *(f4*)(Wrow + 8*u + 4)  = w2;
    *(f4*)(Wrow + 64 + 8*u)     = w1;
    *(f4*)(Wrow + 64 + 8*u + 4) = w3;
    __syncthreads();

    float acc[4][8];
    #pragma unroll
    for (int i=0;i<4;i++){
        #pragma unroll
        for (int j=0;j<8;j++) acc[i][j]=0.f;
    }

    int k0 = 0;
    while (true){
        const int kn = k0 + 32;
        const bool more = kn < K2;
        if (more){
            a0 = *(const f4*)(Ap + kn);
            a1 = *(const f4*)(Ap + kn + 4);
            w0 = *(const f4*)(Wp + (size_t)kn*N);
            w1 = *(const f4*)(Wp + (size_t)kn*N + 4);
            w2 = *(const f4*)(Wp + (size_t)kn*N + 8);
            w3 = *(const f4*)(Wp + (size_t)kn*N + 12);
        }
        #pragma unroll
        for (int kk=0;kk<32;kk++){
            f4 a  = *(const f4*)&As[kh][kk][ty*4];
            f4 wA = *(const f4*)&Ws[kh][kk][tx*4];
            f4 wB = *(const f4*)&Ws[kh][kk][64 + tx*4];
            float ar[4] = {a.x,a.y,a.z,a.w};
            #pragma unroll
            for (int i=0;i<4;i++){
                acc[i][0] += ar[i]*wA.x;
                acc[i][1] += ar[i]*wA.y;
                acc[i][2] += ar[i]*wA.z;
                acc[i][3] += ar[i]*wA.w;
                acc[i][4] += ar[i]*wB.x;
                acc[i][5] += ar[i]*wB.y;
                acc[i][6] += ar[i]*wB.z;
                acc[i][7] += ar[i]*wB.w;
            }
        }
        __syncthreads();
        if (!more) break;
        As[kh][ak+0][am]=a0.x; As[kh][ak+1][am]=a0.y; As[kh][ak+2][am]=a0.z; As[kh][ak+3][am]=a0.w;
        As[kh][ak+4][am]=a1.x; As[kh][ak+5][am]=a1.y; As[kh][ak+6][am]=a1.z; As[kh][ak+7][am]=a1.w;
        *(f4*)(Wrow + 8*u)      = w0;
        *(f4*)(Wrow + 8*u + 4)  = w2;
        *(f4*)(Wrow + 64 + 8*u)     = w1;
        *(f4*)(Wrow + 64 + 8*u + 4) = w3;
        __syncthreads();
        k0 = kn;
    }

    float* cs = &Ws[0][0][0];
    if (kh == 1){
        #pragma unroll
        for (int i=0;i<4;i++){
            #pragma unroll
            for (int b=0;b<2;b++){
                f4 p;
                p.x=acc[i][b*4+0]; p.y=acc[i][b*4+1]; p.z=acc[i][b*4+2]; p.w=acc[i][b*4+3];
                *(f4*)(cs + 4*(((i<<1)|b)*256 + t)) = p;
            }
        }
    }
    __syncthreads();
    if (kh == 0){
        #pragma unroll
        for (int i=0;i<4;i++){
            #pragma unroll
            for (int b=0;b<2;b++){
                const f4 p = *(const f4*)(cs + 4*(((i<<1)|b)*256 + t));
                acc[i][b*4+0]+=p.x; acc[i][b*4+1]+=p.y; acc[i][b*4+2]+=p.z; acc[i][b*4+3]+=p.w;
            }
        }
        #pragma unroll
        for (int i=0;i<4;i++){
            const int r = row0 + ty*4 + i;
            #pragma unroll
            for (int half=0; half<2; ++half){
                const int cb = col0 + tx*8 + half*4;
                f4 bv = *(const f4*)(bias + cb);
                float t0 = acc[i][half*4+0] + bv.x;
                float t1 = acc[i][half*4+1] + bv.y;
                float t2 = acc[i][half*4+2] + bv.z;
                float t3 = acc[i][half*4+3] + bv.w;
                if (act==1){ t0=fmaxf(t0,0.f); t1=fmaxf(t1,0.f); t2=fmaxf(t2,0.f); t3=fmaxf(t3,0.f); }
                else if (act==2){ t0=gelu_f(t0); t1=gelu_f(t1); t2=gelu_f(t2); t3=gelu_f(t3); }
                if (hasres){
                    f4 rv = *(const f4*)(res + (size_t)r*N + cb);
                    t0+=rv.x; t1+=rv.y; t2+=rv.z; t3+=rv.w;
                }
                f4 o; o.x=t0; o.y=t1; o.z=t2; o.w=t3;
                *(f4*)(C + (size_t)r*N + cb) = o;
            }
        }
    }
}

__global__ __launch_bounds__(256) void lnrow(
    const float* __restrict__ X, const float* __restrict__ g,
    const float* __restrict__ b, float* __restrict__ out, float eps)
{
    __shared__ float red[4];
    const int row = blockIdx.x, tid = threadIdx.x;
    const float* xp = X + (size_t)row*D_MOD;
    f4 xv = *(const f4*)(xp + tid*4);
    float s = xv.x+xv.y+xv.z+xv.w;
    #pragma unroll
    for (int m=1;m<64;m<<=1) s += __shfl_xor(s, m);
    const int wid = tid>>6, lane = tid&63;
    if (lane==0) red[wid]=s;
    __syncthreads();
    float mean = (red[0]+red[1]+red[2]+red[3]) * (1.0f/1024.0f);
    __syncthreads();
    float d0=xv.x-mean, d1=xv.y-mean, d2=xv.z-mean, d3=xv.w-mean;
    float q = d0*d0+d1*d1+d2*d2+d3*d3;
    #pragma unroll
    for (int m=1;m<64;m<<=1) q += __shfl_xor(q, m);
    if (lane==0) red[wid]=q;
    __syncthreads();
    float var = (red[0]+red[1]+red[2]+red[3]) * (1.0f/1024.0f);
    float inv = rsqrtf(var + eps);
    f4 gv = *(const f4*)(g + tid*4);
    f4 bv = *(const f4*)(b + tid*4);
    f4 o;
    o.x = d0*inv*gv.x + bv.x;
    o.y = d1*inv*gv.y + bv.y;
    o.z = d2*inv*gv.z + bv.z;
    o.w = d3*inv*gv.w + bv.w;
    *(f4*)(out + (size_t)row*D_MOD + tid*4) = o;
}

// flash attention, QBLK=128, s-split=2, 512 threads (8 waves, 2/SIMD).
// R8: K/V staging loads moved into the post-PV window (short live range for
// kr/vr) -> peak live regs ~105 < 128 cap -> no scratch spill. K/V panels are
// L2-resident (FETCH 21MB), so the exposed L2 latency (~300cyc/tile) is cheap.
#define KS4(r) ((f4*)&ks[r][0])
#define VS4(r) ((f4*)&vs[r][0])
#define QS4(r) ((f4*)&qs[r][0])
__global__ __launch_bounds__(512,1) void attn128s(
    const float* __restrict__ Q, const float* __restrict__ Kb,
    const float* __restrict__ Vb,
    float* __restrict__ OA0, float* __restrict__ OA1,
    float* __restrict__ ML0, float* __restrict__ ML1)
{
    __shared__ float qs[128][132];
    __shared__ float ks[64][132];   // K tile; P[s][q] alias between b1..b3
    __shared__ float vs[64][132];
    __shared__ float scs[128];
    const int tid = threadIdx.x;
    const int h  = blockIdx.x & 7;
    const int sh = (blockIdx.x >> 3) & 1;
    const int q0 = (blockIdx.x >> 4) * 128;
    const int dh = tid & 1;
    const int sg = (tid >> 1) & 15;
    const int qg = tid >> 5;
    const int qg2 = tid >> 4;
    const int dg  = tid & 15;
    const int c4 = tid & 31, rb = tid >> 5;
    const int sbase = sh * 1024;
    const float qscale = 0.08838834764831845f; // 1/sqrt(128)

    // stage tile 0 (loads have short live range)
    {
        f4 kr[4], vr[4];
        #pragma unroll
        for (int j=0;j<4;j++){
            const int r = rb + 16*j;
            kr[j] = *(const f4*)(Kb + (size_t)(sbase+r)*D_MOD + h*128 + c4*4);
            vr[j] = *(const f4*)(Vb + (size_t)(sbase+r)*D_MOD + h*128 + c4*4);
        }
        #pragma unroll
        for (int kq=0;kq<8;kq++){
            const int i = tid + kq*512;
            const int r = i>>5, cc = i&31;
            f4 v = *(const f4*)(Q + (size_t)(q0+r)*D_MOD + h*128 + cc*4);
            v.x*=qscale; v.y*=qscale; v.z*=qscale; v.w*=qscale;
            QS4(r)[cc ^ ((r>>2)&7)] = v;
        }
        #pragma unroll
        for (int j=0;j<4;j++){
            const int r = rb + 16*j;
            const int key = (r>>2)&7;
            KS4(r)[c4 ^ key] = kr[j];
            VS4(r)[c4 ^ key] = vr[j];
        }
    }
    __syncthreads();

    float mstat[8], lstat[8];
    f4 oa[4][2];
    #pragma unroll
    for (int i=0;i<8;i++){ mstat[i] = -__builtin_inff(); lstat[i] = 0.f; }
    #pragma unroll
    for (int i=0;i<4;i++){
        #pragma unroll
        for (int b=0;b<2;b++){ oa[i][b].x=0.f; oa[i][b].y=0.f; oa[i][b].z=0.f; oa[i][b].w=0.f; }
    }

    for (int t=0; t<16; ++t){
        // ---- QK^T: acc[8q][4s] over this thread's 64-d half ----
        float acc[8][4];
        #pragma unroll
        for (int i=0;i<8;i++){
            #pragma unroll
            for (int j=0;j<4;j++) acc[i][j]=0.f;
        }
        #pragma unroll
        for (int c=0;c<16;c++){
            const int ch = dh*16 + c;
            f4 kv[4];
            #pragma unroll
            for (int j=0;j<4;j++) kv[j] = KS4(sg*4+j)[ch ^ (sg&7)];
            #pragma unroll
            for (int i=0;i<8;i++){
                const f4 qv = QS4(qg*8+i)[ch ^ ((qg*2+(i>>2))&7)];
                #pragma unroll
                for (int j=0;j<4;j++)
                    acc[i][j] += qv.x*kv[j].x + qv.y*kv[j].y + qv.z*kv[j].z + qv.w*kv[j].w;
            }
        }
        __syncthreads();   // b1: ks region free (K_t consumed)

        // ---- combine d-halves + online softmax ----
        float scarr[8];
        #pragma unroll
        for (int i=0;i<8;i++){
            #pragma unroll
            for (int j=0;j<4;j++) acc[i][j] += __shfl_xor(acc[i][j], 1);
            float tm = fmaxf(fmaxf(acc[i][0],acc[i][1]), fmaxf(acc[i][2],acc[i][3]));
            tm = fmaxf(tm, __shfl_xor(tm,2));
            tm = fmaxf(tm, __shfl_xor(tm,4));
            tm = fmaxf(tm, __shfl_xor(tm,8));
            tm = fmaxf(tm, __shfl_xor(tm,16));
            const float mn = fmaxf(mstat[i], tm);
            const float sc = __expf(mstat[i] - mn);
            float rs = 0.f;
            #pragma unroll
            for (int j=0;j<4;j++){
                const float p = __expf(acc[i][j] - mn);
                acc[i][j] = p; rs += p;
            }
            rs += __shfl_xor(rs,2); rs += __shfl_xor(rs,4);
            rs += __shfl_xor(rs,8); rs += __shfl_xor(rs,16);
            lstat[i] = lstat[i]*sc + rs;
            mstat[i] = mn;
            scarr[i] = sc;
        }
        // write P (transposed [s][q]) into ks region; write per-q scales
        if (dh == 0){
            #pragma unroll
            for (int j=0;j<4;j++){
                const int s = sg*4 + j;
                f4 pw0, pw1;
                pw0.x=acc[0][j]; pw0.y=acc[1][j]; pw0.z=acc[2][j]; pw0.w=acc[3][j];
                pw1.x=acc[4][j]; pw1.y=acc[5][j]; pw1.z=acc[6][j]; pw1.w=acc[7][j];
                KS4(s)[2*qg]   = pw0;
                KS4(s)[2*qg+1] = pw1;
            }
            if (sg == 0){
                f4 s0, s1;
                s0.x=scarr[0]; s0.y=scarr[1]; s0.z=scarr[2]; s0.w=scarr[3];
                s1.x=scarr[4]; s1.y=scarr[5]; s1.z=scarr[6]; s1.w=scarr[7];
                ((f4*)scs)[2*qg]   = s0;
                ((f4*)scs)[2*qg+1] = s1;
            }
        }
        __syncthreads();   // b2: P + scales ready

        // ---- PV: thread owns 4 q rows x 8 d; iterate all 64 s ----
        {
            const f4 scf = ((const f4*)scs)[qg2];
            #pragma unroll
            for (int b=0;b<2;b++){
                oa[0][b].x*=scf.x; oa[0][b].y*=scf.x; oa[0][b].z*=scf.x; oa[0][b].w*=scf.x;
                oa[1][b].x*=scf.y; oa[1][b].y*=scf.y; oa[1][b].z*=scf.y; oa[1][b].w*=scf.y;
                oa[2][b].x*=scf.z; oa[2][b].y*=scf.z; oa[2][b].z*=scf.z; oa[2][b].w*=scf.z;
                oa[3][b].x*=scf.w; oa[3][b].y*=scf.w; oa[3][b].z*=scf.w; oa[3][b].w*=scf.w;
            }
        }
        #pragma unroll 4
        for (int s=0; s<64; ++s){
            const int vkey = (s>>2)&7;
            const f4 pv = KS4(s)[qg2];
            const f4 v0 = VS4(s)[(2*dg)   ^ vkey];
            const f4 v1 = VS4(s)[(2*dg+1) ^ vkey];
            oa[0][0].x+=pv.x*v0.x; oa[0][0].y+=pv.x*v0.y; oa[0][0].z+=pv.x*v0.z; oa[0][0].w+=pv.x*v0.w;
            oa[0][1].x+=pv.x*v1.x; oa[0][1].y+=pv.x*v1.y; oa[0][1].z+=pv.x*v1.z; oa[0][1].w+=pv.x*v1.w;
            oa[1][0].x+=pv.y*v0.x; oa[1][0].y+=pv.y*v0.y; oa[1][0].z+=pv.y*v0.z; oa[1][0].w+=pv.y*v0.w;
            oa[1][1].x+=pv.y*v1.x; oa[1][1].y+=pv.y*v1.y; oa[1][1].z+=pv.y*v1.z; oa[1][1].w+=pv.y*v1.w;
            oa[2][0].x+=pv.z*v0.x; oa[2][0].y+=pv.z*v0.y; oa[2][0].z+=pv.z*v0.z; oa[2][0].w+=pv.z*v0.w;
            oa[2][1].x+=pv.z*v1.x; oa[2][1].y+=pv.z*v1.y; oa[2][1].z+=pv.z*v1.z; oa[2][1].w+=pv.z*v1.w;
            oa[3][0].x+=pv.w*v0.x; oa[3][0].y+=pv.w*v0.y; oa[3][0].z+=pv.w*v0.z; oa[3][0].w+=pv.w*v0.w;
            oa[3][1].x+=pv.w*v1.x; oa[3][1].y+=pv.w*v1.y; oa[3][1].z+=pv.w*v1.z; oa[3][1].w+=pv.w*v1.w;
        }
        __syncthreads();   // b3: ks (P) and vs (V_t) free

        if (t < 15){
            // load AND write K/V tile t+1 in one short window (no long-lived regs)
            f4 kr[4], vr[4];
            const int gb = sbase + (t+1)*64;
            #pragma unroll
            for (int j=0;j<4;j++){
                const int gr = gb + rb + 16*j;
                kr[j] = *(const f4*)(Kb + (size_t)gr*D_MOD + h*128 + c4*4);
                vr[j] = *(const f4*)(Vb + (size_t)gr*D_MOD + h*128 + c4*4);
            }
            #pragma unroll
            for (int j=0;j<4;j++){
                const int r = rb + 16*j;
                const int key = (r>>2)&7;
                KS4(r)[c4 ^ key] = kr[j];
                VS4(r)[c4 ^ key] = vr[j];
            }
        }
        __syncthreads();   // b4: K_{t+1}/V_{t+1} staged before next QK
    }

    float* OAp = sh ? OA1 : OA0;
    float* MLp = sh ? ML1 : ML0;
    #pragma unroll
    for (int i=0;i<4;i++){
        float* dst = OAp + (size_t)(q0+qg2*4+i)*D_MOD + h*128 + dg*8;
        *(f4*)dst     = oa[i][0];
        *(f4*)(dst+4) = oa[i][1];
    }
    if (dh == 0 && sg == 0){
        #pragma unroll
        for (int i=0;i<8;i++){
            MLp[(size_t)(q0+qg*8+i)*16 + h*2 + 0] = mstat[i];
            MLp[(size_t)(q0+qg*8+i)*16 + h*2 + 1] = lstat[i];
        }
    }
}

// flash-combine of the two s-halves + the bias-KV token (exact softmax algebra)
__global__ __launch_bounds__(256) void attn_combine(
    const float* __restrict__ Q, const float* __restrict__ kbias,
    const float* __restrict__ vbias,
    const float* __restrict__ OA0, const float* __restrict__ OA1,
    const float* __restrict__ ML0, const float* __restrict__ ML1,
    float* __restrict__ O)
{
    const int row = blockIdx.x, t = threadIdx.x;
    const int h = t >> 5;
    const int cc = t & 31;
    const float qscale = 0.08838834764831845f;
    const f4 qv = *(const f4*)(Q + (size_t)row*D_MOD + h*128 + cc*4);
    const f4 kb = *(const f4*)(kbias + h*128 + cc*4);
    float part = qv.x*kb.x + qv.y*kb.y + qv.z*kb.z + qv.w*kb.w;
    part += __shfl_xor(part,1); part += __shfl_xor(part,2);
    part += __shfl_xor(part,4); part += __shfl_xor(part,8);
    part += __shfl_xor(part,16);
    const float sb = part * qscale;
    const float m0 = ML0[(size_t)row*16 + h*2], l0 = ML0[(size_t)row*16 + h*2 + 1];
    const float m1 = ML1[(size_t)row*16 + h*2], l1 = ML1[(size_t)row*16 + h*2 + 1];
    const float M  = fmaxf(fmaxf(m0, m1), sb);
    const float w0 = __expf(m0 - M), w1 = __expf(m1 - M), wb = __expf(sb - M);
    const float inv = 1.0f / (w0*l0 + w1*l1 + wb);
    const f4 o0 = *(const f4*)(OA0 + (size_t)row*D_MOD + t*4);
    const f4 o1 = *(const f4*)(OA1 + (size_t)row*D_MOD + t*4);
    const f4 vb = *(const f4*)(vbias + h*128 + cc*4);
    f4 o;
    o.x = (o0.x*w0 + o1.x*w1 + vb.x*wb) * inv;
    o.y = (o0.y*w0 + o1.y*w1 + vb.y*wb) * inv;
    o.z = (o0.z*w0 + o1.z*w1 + vb.z*wb) * inv;
    o.w = (o0.w*w0 + o1.w*w1 + vb.w*wb) * inv;
    *(f4*)(O + (size_t)row*D_MOD + t*4) = o;
}

__global__ __launch_bounds__(64) void locate_head(
    const float* __restrict__ mid, const float* __restrict__ W2,
    const float* __restrict__ b2, float* __restrict__ loc_ws,
    float* __restrict__ loc_out)
{
    const int row = blockIdx.x, lane = threadIdx.x;
    const float* m = mid + (size_t)row*512;
    f4 v0 = *(const f4*)(m + lane*8);
    f4 v1 = *(const f4*)(m + lane*8 + 4);
    f4 w0 = *(const f4*)(W2 + lane*8);
    f4 w1 = *(const f4*)(W2 + lane*8 + 4);
    float s = v0.x*w0.x + v0.y*w0.y + v0.z*w0.z + v0.w*w0.w
            + v1.x*w1.x + v1.y*w1.y + v1.z*w1.z + v1.w*w1.w;
    #pragma unroll
    for (int mm=1; mm<64; mm<<=1) s += __shfl_xor(s, mm);
    if (lane==0){
        float z = s + b2[0];
        float l = 1.0f/(1.0f + expf(-z));
        loc_ws[row] = l;
        loc_out[row] = l;
    }
}

__global__ __launch_bounds__(1024) void segscan(
    const float* __restrict__ located, const float* __restrict__ thrp,
    float* __restrict__ out_segid, float* __restrict__ out_segtype,
    float* __restrict__ out_numseg, int* __restrict__ wsi)
{
    __shared__ int clips[2048];
    __shared__ int segid[2048];
    __shared__ int sstart[2049];
    __shared__ int wsum[16];
    const int tid = threadIdx.x;
    const float thr = *thrp;
    for (int t=tid; t<2048; t+=1024) clips[t] = (located[t] > thr) ? 1 : 0;
    __syncthreads();
    const int t0 = tid*2, t1 = t0+1;
    int f0 = (t0==0) ? 0 : (clips[t0]!=clips[t0-1] ? 1 : 0);
    int f1 = (clips[t1]!=clips[t1-1] ? 1 : 0);
    int e0 = f0, e1 = f0+f1;
    const int lane = tid&63, wid = tid>>6;
    int v = e1;
    #pragma unroll
    for (int off=1; off<64; off<<=1){
        int u = __shfl_up(v, off, 64);
        if (lane>=off) v += u;
    }
    if (lane==63) wsum[wid] = v;
    __syncthreads();
    if (tid < 16){
        int w = wsum[tid];
        #pragma unroll
        for (int off=1; off<16; off<<=1){
            int u = __shfl_up(w, off, 16);
            if (tid>=off) w += u;
        }
        wsum[tid] = w;
    }
    __syncthreads();
    int base = (wid>0 ? wsum[wid-1] : 0) + (v - e1);
    segid[t0] = base + e0;
    segid[t1] = base + e1;
    __syncthreads();
    const int ns = segid[2047] + 1;
    for (int t=tid; t<2048; t+=1024){
        if (t==0 || segid[t]!=segid[t-1]) sstart[segid[t]] = t;
    }
    if (tid==0) sstart[ns] = 2048;
    __syncthreads();
    for (int t=tid; t<2048; t+=1024) out_segid[t] = (float)segid[t];
    for (int s=tid; s<2048; s+=1024)
        out_segtype[s] = (s<ns) ? (float)clips[sstart[s]] : -2147483648.0f;
    if (tid==0){ out_numseg[0] = (float)ns; wsi[0] = ns; }
    for (int s=tid; s<=2048; s+=1024) wsi[2+s] = (s<=ns) ? sstart[s] : 0;
}

__global__ __launch_bounds__(256) void segpool(
    const float* __restrict__ V, const float* __restrict__ A,
    const int* __restrict__ wsi, float* __restrict__ out_vid,
    float* __restrict__ out_aud)
{
    const int s = blockIdx.x;
    const int c = threadIdx.x*4;
    const int ns = wsi[0];
    f4 vv; vv.x=0.f; vv.y=0.f; vv.z=0.f; vv.w=0.f;
    f4 av = vv;
    if (s < ns){
        const int st = wsi[2+s], en = wsi[2+s+1];
        for (int r=st; r<en; ++r){
            f4 x = *(const f4*)(V + (size_t)r*D_MOD + c);
            vv.x+=x.x; vv.y+=x.y; vv.z+=x.z; vv.w+=x.w;
            f4 y = *(const f4*)(A + (size_t)r*D_MOD + c);
            av.x+=y.x; av.y+=y.y; av.z+=y.z; av.w+=y.w;
        }
        const float inv = 1.0f/(float)(en-st);
        vv.x*=inv; vv.y*=inv; vv.z*=inv; vv.w*=inv;
        av.x*=inv; av.y*=inv; av.z*=inv; av.w*=inv;
    }
    *(f4*)(out_vid + (size_t)s*D_MOD + c) = vv;
    *(f4*)(out_aud + (size_t)s*D_MOD + c) = av;
}

extern "C" void kernel_launch(void* const* d_in, const int* in_sizes, int n_in,
                              void* d_out, int out_size, void* d_ws, size_t ws_size,
                              hipStream_t stream) {
    (void)in_sizes; (void)n_in; (void)out_size; (void)ws_size;
    const float* video = (const float*)d_in[0];
    const float* audio = (const float*)d_in[1];
    const float* apW1  = (const float*)d_in[2];
    const float* apb1  = (const float*)d_in[3];
    const float* apW2  = (const float*)d_in[4];
    const float* apb2  = (const float*)d_in[5];
    const float* vpW1  = (const float*)d_in[6];
    const float* vpb1  = (const float*)d_in[7];
    const float* vpW2  = (const float*)d_in[8];
    const float* vpb2  = (const float*)d_in[9];
    const float* preg  = (const float*)d_in[10];
    const float* preb  = (const float*)d_in[11];
    const float* bWq   = (const float*)d_in[12];
    const float* bbq   = (const float*)d_in[13];
    const float* bWk   = (const float*)d_in[14];
    const float* bbk   = (const float*)d_in[15];
    const float* bWv   = (const float*)d_in[16];
    const float* bbv   = (const float*)d_in[17];
    const float* bWo   = (const float*)d_in[18];
    const float* bbo   = (const float*)d_in[19];
    const float* bbiask= (const float*)d_in[20];
    const float* bbiasv= (const float*)d_in[21];
    const float* bg1   = (const float*)d_in[22];
    const float* bb1   = (const float*)d_in[23];
    const float* bg2   = (const float*)d_in[24];
    const float* bb2   = (const float*)d_in[25];
    const float* bmW1  = (const float*)d_in[26];
    const float* bmb1  = (const float*)d_in[27];
    const float* bmW2  = (const float*)d_in[28];
    const float* bmb2  = (const float*)d_in[29];
    const float* lhW1  = (const float*)d_in[30];
    const float* lhb1  = (const float*)d_in[31];
    const float* lhW2  = (const float*)d_in[32];
    const float* lhb2  = (const float*)d_in[33];
    const float* thrp  = (const float*)d_in[34];

    float* ws = (float*)d_ws;
    float* V    = ws + 0;
    float* Abuf = ws + 2097152;
    float* X    = ws + 4194304;
    float* H    = ws + 6291456;             // OA1 during attention (dead there)
    float* Q    = ws + 8388608;
    float* Kb   = ws + 10485760;            // 2048*1024
    float* Vb   = ws + 12582912;            // 2048*1024
    float* Obuf = ws + 14680064;            // 2048*1024; OA0 during attention
    float* M4   = ws + 8388608;             // 2048*4096, aliases Q..Obuf
    float* M512 = ws + 16777216;            // 2048*512
    float* LOC  = ws + 17825792;            // 2048
    int*   WSI  = (int*)(ws + 17827840);    // 2051 ints
    float* ML0  = ws + 17829952;            // 2048*8*2
    float* ML1  = ws + 17862720;            // 2048*8*2

    float* out = (float*)d_out;
    float* out_vid     = out + 0;
    float* out_aud     = out + 2097152;
    float* out_loc     = out + 4194304;
    float* out_segid   = out + 4196352;
    float* out_segtype = out + 4198400;
    float* out_numseg  = out + 4200448;

    const dim3 B512(512);
    const dim3 B256(256);
    #define GRID128(M,N) dim3((N)/128,(M)/64)

    // projectors
    gemm128k2<<<GRID128(2048,512), B512, 0, stream>>>(audio, apW1, apb1, nullptr, M512, 2048,512,128, 1,0);
    gemm128k2<<<GRID128(2048,1024),B512, 0, stream>>>(M512, apW2, apb2, nullptr, Abuf, 2048,1024,512, 0,0);
    gemm128k2<<<GRID128(2048,512), B512, 0, stream>>>(video, vpW1, vpb1, nullptr, M512, 2048,512,1024, 1,0);
    gemm128k2<<<GRID128(2048,1024),B512, 0, stream>>>(M512, vpW2, vpb2, nullptr, V,    2048,1024,512, 0,0);
    lnrow<<<2048, B256, 0, stream>>>(Abuf, preg, preb, X, 1e-6f);

    for (int l=0; l<8; ++l){
        const size_t wo = (size_t)l*1024*1024;
        const size_t bo = (size_t)l*1024;
        const size_t mo1 = (size_t)l*1024*4096;
        lnrow<<<2048, B256, 0, stream>>>(X, bg1+bo, bb1+bo, H, 1e-5f);
        gemm128k2<<<GRID128(2048,1024),B512,0,stream>>>(H, bWq+wo, bbq+bo, nullptr, Q,  2048,1024,1024, 0,0);
        gemm128k2<<<GRID128(2048,1024),B512,0,stream>>>(V, bWk+wo, bbk+bo, nullptr, Kb, 2048,1024,1024, 0,0);
        gemm128k2<<<GRID128(2048,1024),B512,0,stream>>>(V, bWv+wo, bbv+bo, nullptr, Vb, 2048,1024,1024, 0,0);
        attn128s<<<256, B512, 0, stream>>>(Q, Kb, Vb, Obuf, H, ML0, ML1);
        attn_combine<<<2048, B256, 0, stream>>>(Q, bbiask+bo, bbiasv+bo, Obuf, H, ML0, ML1, Obuf);
        gemm128k2<<<GRID128(2048,1024),B512,0,stream>>>(Obuf, bWo+wo, bbo+bo, X, X, 2048,1024,1024, 0,1);
        lnrow<<<2048, B256, 0, stream>>>(X, bg2+bo, bb2+bo, H, 1e-5f);
        gemm128k2<<<GRID128(2048,4096),B512,0,stream>>>(H, bmW1+mo1, bmb1+(size_t)l*4096, nullptr, M4, 2048,4096,1024, 2,0);
        gemm128k2<<<GRID128(2048,1024),B512,0,stream>>>(M4, bmW2+mo1, bmb2+bo, X, X, 2048,1024,4096, 0,1);
    }

    gemm128k2<<<GRID128(2048,512), B512, 0, stream>>>(X, lhW1, lhb1, nullptr, M512, 2048,512,1024, 1,0);
    locate_head<<<2048, dim3(64), 0, stream>>>(M512, lhW2, lhb2, LOC, out_loc);
    segscan<<<1, dim3(1024), 0, stream>>>(LOC, thrp, out_segid, out_segtype, out_numseg, WSI);
    segpool<<<2048, B256, 0, stream>>>(V, Abuf, WSI, out_vid, out_aud);
}